// Round 1
// baseline (4795.025 us; speedup 1.0000x reference)
//
#include <hip/hip_runtime.h>

// ---------------------------------------------------------------------------
// Problem constants
//   S=512 tokens, WD=300, TD=100, CE=20, CH=20, H=512, LAB=50, MAXW=16
// Outputs: arc_scores (512x512) | label_scores (50x512) | char_embeds (20x512)
// ---------------------------------------------------------------------------

static __device__ __forceinline__ float sigm(float x) { return 1.f / (1.f + __expf(-x)); }
static __device__ __forceinline__ float ftanh(float x) {
    x = fminf(15.f, fmaxf(-15.f, x));
    float e = __expf(2.f * x);
    return (e - 1.f) / (e + 1.f);
}
static __device__ __forceinline__ unsigned f2bf(float x) {
    union { float f; unsigned u; } v; v.f = x;
    unsigned r = v.u + 0x7fffu + ((v.u >> 16) & 1u);
    return r >> 16;  // bf16 bits in low 16
}
static __device__ __forceinline__ float bflo(unsigned u) {
    union { unsigned u; float f; } v; v.u = u << 16; return v.f;
}
static __device__ __forceinline__ float bfhi(unsigned u) {
    union { unsigned u; float f; } v; v.u = u & 0xffff0000u; return v.f;
}

// ---------------------------------------------------------------------------
// Embedding gather: embeds[t][0:300]=word_emb[sentence[t]], [300:400]=tag_emb[tags[t]]
// ---------------------------------------------------------------------------
__global__ void gather_k(const int* __restrict__ sentence, const int* __restrict__ tags,
                         const float* __restrict__ word_emb, const float* __restrict__ tag_emb,
                         float* __restrict__ embeds) {
    int t = blockIdx.x;
    int w = sentence[t], tg = tags[t];
    for (int j = threadIdx.x; j < 400; j += blockDim.x) {
        float v = (j < 300) ? word_emb[w * 300 + j] : tag_emb[tg * 100 + (j - 300)];
        embeds[t * 400 + j] = v;
    }
}

// ---------------------------------------------------------------------------
// Generic fp32 GEMM: C[M,N] = A[M,K] @ B[N,K]^T (+ bias[n*bias_stride]) (opt relu)
// Requires M%64==0, N%64==0, K%16==0. revA: A rows read reversed.
// block 256 threads, 64x64 tile, 4x4 per thread.
// ---------------------------------------------------------------------------
__global__ __launch_bounds__(256) void gemm_abT(
    const float* __restrict__ A, int lda, const float* __restrict__ B, int ldb,
    const float* __restrict__ bias, int bias_stride,
    float* __restrict__ C, int ldc, int M, int N, int K, int revA, int doRelu) {
    __shared__ float As[16][65];
    __shared__ float Bs[16][65];
    int tx = threadIdx.x & 15, ty = threadIdx.x >> 4;
    int bm = blockIdx.y * 64, bn = blockIdx.x * 64;
    float acc[4][4] = {};
    for (int k0 = 0; k0 < K; k0 += 16) {
#pragma unroll
        for (int i = 0; i < 4; ++i) {
            int e = threadIdx.x + i * 256;   // 0..1023
            int m = e >> 4, kk = e & 15;
            int row = bm + m; if (revA) row = M - 1 - row;
            As[kk][m] = A[(size_t)row * lda + k0 + kk];
            Bs[kk][m] = B[(size_t)(bn + m) * ldb + k0 + kk];
        }
        __syncthreads();
#pragma unroll
        for (int kk = 0; kk < 16; ++kk) {
            float a0 = As[kk][ty * 4 + 0], a1 = As[kk][ty * 4 + 1];
            float a2 = As[kk][ty * 4 + 2], a3 = As[kk][ty * 4 + 3];
            float b0 = Bs[kk][tx * 4 + 0], b1 = Bs[kk][tx * 4 + 1];
            float b2 = Bs[kk][tx * 4 + 2], b3 = Bs[kk][tx * 4 + 3];
            acc[0][0] += a0 * b0; acc[0][1] += a0 * b1; acc[0][2] += a0 * b2; acc[0][3] += a0 * b3;
            acc[1][0] += a1 * b0; acc[1][1] += a1 * b1; acc[1][2] += a1 * b2; acc[1][3] += a1 * b3;
            acc[2][0] += a2 * b0; acc[2][1] += a2 * b1; acc[2][2] += a2 * b2; acc[2][3] += a2 * b3;
            acc[3][0] += a3 * b0; acc[3][1] += a3 * b1; acc[3][2] += a3 * b2; acc[3][3] += a3 * b3;
        }
        __syncthreads();
    }
#pragma unroll
    for (int i = 0; i < 4; ++i) {
#pragma unroll
        for (int j = 0; j < 4; ++j) {
            int n = bn + tx * 4 + j;
            float v = acc[i][j];
            if (bias) v += bias[(size_t)n * bias_stride];
            if (doRelu) v = fmaxf(v, 0.f);
            C[(size_t)(bm + ty * 4 + i) * ldc + n] = v;
        }
    }
}

// ---------------------------------------------------------------------------
// Recurrent bidirectional LSTM. 32 WGs: dir = wg>>4, slice s = wg&15.
// Each WG owns h-dims [s*32, s*32+32) => 128 rows of W_hh, held in VGPRs as
// packed bf16 (uint = 2 cols). Thread (g = tid&31, p = tid>>5): rows q*32+g
// over cols [p*64, p*64+64). Per step: stage h (agent atomics, ping-pong
// buffers), FMA, LDS reduce over p, gate math on 32 lanes, release/acquire
// counter barrier across the direction's 16 WGs.
// ---------------------------------------------------------------------------
__global__ __launch_bounds__(256) void lstm_rec(
    const float* __restrict__ W_hh_f, const float* __restrict__ W_hh_b,
    const float* __restrict__ xpf, const float* __restrict__ xpb,
    float* __restrict__ lstm_out, float* hG, unsigned* cnt) {
    int wg = blockIdx.x;
    int dir = wg >> 4, s = wg & 15;
    int tid = threadIdx.x;
    int g = tid & 31, p = tid >> 5;
    const float* Whh = dir ? W_hh_b : W_hh_f;
    const float* xp = dir ? xpb : xpf;

    __shared__ float hsh[512];
    __shared__ float red[8 * 128];  // [p][g][q]

    unsigned Wreg[4][32];
#pragma unroll
    for (int q = 0; q < 4; ++q) {
        int gr = q * 512 + s * 32 + g;
        const float* wrow = Whh + (size_t)gr * 512 + p * 64;
#pragma unroll
        for (int u = 0; u < 32; ++u) {
            unsigned lo = f2bf(wrow[2 * u]);
            unsigned hi = f2bf(wrow[2 * u + 1]);
            Wreg[q][u] = lo | (hi << 16);
        }
    }

    float c = 0.f;
    unsigned* mycnt = cnt + dir * 32;      // 128 B apart
    float* hbase = hG + dir * 1024;        // 2 ping-pong buffers of 512

    for (int t = 0; t < 512; ++t) {
        float* hin = hbase + (t & 1) * 512;
        for (int i = tid; i < 512; i += 256)
            hsh[i] = __hip_atomic_load(hin + i, __ATOMIC_RELAXED, __HIP_MEMORY_SCOPE_AGENT);
        __syncthreads();

        float a0 = 0.f, a1 = 0.f, a2 = 0.f, a3 = 0.f;
        const float* hv = hsh + p * 64;
#pragma unroll
        for (int u = 0; u < 32; ++u) {
            float h0 = hv[2 * u], h1 = hv[2 * u + 1];
            unsigned w0 = Wreg[0][u]; a0 += bflo(w0) * h0; a0 += bfhi(w0) * h1;
            unsigned w1 = Wreg[1][u]; a1 += bflo(w1) * h0; a1 += bfhi(w1) * h1;
            unsigned w2 = Wreg[2][u]; a2 += bflo(w2) * h0; a2 += bfhi(w2) * h1;
            unsigned w3 = Wreg[3][u]; a3 += bflo(w3) * h0; a3 += bfhi(w3) * h1;
        }
        float* r = red + p * 128 + g * 4;
        r[0] = a0; r[1] = a1; r[2] = a2; r[3] = a3;
        __syncthreads();

        if (tid < 32) {
            float z0 = 0.f, z1 = 0.f, z2 = 0.f, z3 = 0.f;
#pragma unroll
            for (int pp = 0; pp < 8; ++pp) {
                const float* rr = red + pp * 128 + tid * 4;
                z0 += rr[0]; z1 += rr[1]; z2 += rr[2]; z3 += rr[3];
            }
            int col = s * 32 + tid;
            const float* x = xp + (size_t)t * 2048;
            z0 += x[col];          // i
            z1 += x[512 + col];    // f
            z2 += x[1024 + col];   // g
            z3 += x[1536 + col];   // o
            c = sigm(z1) * c + sigm(z0) * ftanh(z2);
            float hn = sigm(z3) * ftanh(c);
            __hip_atomic_store(hbase + ((t + 1) & 1) * 512 + col, hn,
                               __ATOMIC_RELAXED, __HIP_MEMORY_SCOPE_AGENT);
            int row = dir ? (511 - t) : t;
            lstm_out[(size_t)row * 1024 + dir * 512 + col] = hn;
        }

        __threadfence();
        __syncthreads();
        if (tid == 0) {
            __hip_atomic_fetch_add(mycnt, 1u, __ATOMIC_ACQ_REL, __HIP_MEMORY_SCOPE_AGENT);
            unsigned target = 16u * (unsigned)(t + 1);
            while (__hip_atomic_load(mycnt, __ATOMIC_ACQUIRE, __HIP_MEMORY_SCOPE_AGENT) < target)
                __builtin_amdgcn_s_sleep(1);
        }
        __syncthreads();
        __threadfence();
    }
}

// ---------------------------------------------------------------------------
// Per-word char LSTM + masked gram attention.
// out[e][w] = sum_{t<L} h_t[e] * (h_t . attW) + att_b   (h_t from full 16-step scan)
// One 64-thread WG per word; lanes 0..19 = h dims.
// ---------------------------------------------------------------------------
__global__ __launch_bounds__(64) void char_k(
    const int* __restrict__ chars, const int* __restrict__ char_lengths,
    const float* __restrict__ char_emb, const float* __restrict__ att_W,
    const float* __restrict__ att_b, const float* __restrict__ cW_ih,
    const float* __restrict__ cW_hh, const float* __restrict__ cb,
    float* __restrict__ out2) {
    int w = blockIdx.x, tid = threadIdx.x;
    __shared__ float Wih[1600], Whh[1600], cbs[80], attsh[20];
    __shared__ float xsh[20], hsh[20], prodsh[20];
    for (int i = tid; i < 1600; i += 64) { Wih[i] = cW_ih[i]; Whh[i] = cW_hh[i]; }
    for (int i = tid; i < 80; i += 64) cbs[i] = cb[i];
    if (tid < 20) { attsh[tid] = att_W[tid]; hsh[tid] = 0.f; }
    __syncthreads();

    int L = char_lengths[w];
    float c = 0.f, accj = 0.f;
    for (int t = 0; t < 16; ++t) {
        if (tid < 20) xsh[tid] = char_emb[(size_t)chars[w * 16 + t] * 20 + tid];
        __syncthreads();
        float hn = 0.f;
        if (tid < 20) {
            float z[4];
#pragma unroll
            for (int q = 0; q < 4; ++q) {
                int r = q * 20 + tid;
                float sacc = cbs[r];
                for (int d = 0; d < 20; ++d)
                    sacc += Wih[r * 20 + d] * xsh[d] + Whh[r * 20 + d] * hsh[d];
                z[q] = sacc;
            }
            c = sigm(z[1]) * c + sigm(z[0]) * ftanh(z[2]);
            hn = sigm(z[3]) * ftanh(c);
        }
        __syncthreads();
        if (tid < 20) { hsh[tid] = hn; prodsh[tid] = hn * attsh[tid]; }
        __syncthreads();
        if (tid < 20 && t < L) {
            float st = 0.f;
            for (int k = 0; k < 20; ++k) st += prodsh[k];
            accj += hn * st;
        }
        __syncthreads();
    }
    if (tid < 20) out2[tid * 512 + w] = accj + att_b[0];
}

// ---------------------------------------------------------------------------
// Build U[t] = [label_head[best_arcs[t]], 1, 0, 0, 0], V[t] = [label_dep[t], 1, 0,0,0]
// (row stride 516, zero-padded past col 512)
// ---------------------------------------------------------------------------
__global__ void uv_k(const int* __restrict__ best_arcs,
                     const float* __restrict__ label_head, const float* __restrict__ label_dep,
                     float* __restrict__ U, float* __restrict__ V) {
    int t = blockIdx.x;
    int ba = best_arcs[t];
    for (int j = threadIdx.x; j < 516; j += blockDim.x) {
        float u = (j < 512) ? label_head[(size_t)ba * 512 + j] : (j == 512 ? 1.f : 0.f);
        float v = (j < 512) ? label_dep[(size_t)t * 512 + j] : (j == 512 ? 1.f : 0.f);
        U[t * 516 + j] = u;
        V[t * 516 + j] = v;
    }
}

// ---------------------------------------------------------------------------
// Label biaffine: sel[l,t] += sum_{k-tile} (U[t,:] @ B_l[:, ktile]) . V[t, ktile]
// grid (ktile=9, ttile=8, l=50), block 256, 64x64 D-tile, 4x4/thread.
// ---------------------------------------------------------------------------
__global__ __launch_bounds__(256) void label_k(
    const float* __restrict__ U, const float* __restrict__ V,
    const float* __restrict__ BW, float* __restrict__ sel) {
    __shared__ float Us[16][65];
    __shared__ float Bs[16][65];
    __shared__ float selred[64];
    int l = blockIdx.z;
    int t0 = blockIdx.y * 64, k0 = blockIdx.x * 64;
    const float* Bl = BW + (size_t)l * 513 * 513;
    int tx = threadIdx.x & 15, ty = threadIdx.x >> 4;
    float acc[4][4] = {};
    for (int h0 = 0; h0 < 513; h0 += 16) {
#pragma unroll
        for (int i = 0; i < 4; ++i) {
            int e = threadIdx.x + i * 256;
            int a = e >> 4, hh = e & 15;
            int h = h0 + hh;
            Us[hh][a] = (h < 513) ? U[(size_t)(t0 + a) * 516 + h] : 0.f;
            int kc = k0 + a;
            Bs[hh][a] = (h < 513 && kc < 513) ? Bl[(size_t)h * 513 + kc] : 0.f;
        }
        __syncthreads();
#pragma unroll
        for (int hh = 0; hh < 16; ++hh) {
            float a0 = Us[hh][ty * 4 + 0], a1 = Us[hh][ty * 4 + 1];
            float a2 = Us[hh][ty * 4 + 2], a3 = Us[hh][ty * 4 + 3];
            float b0 = Bs[hh][tx * 4 + 0], b1 = Bs[hh][tx * 4 + 1];
            float b2 = Bs[hh][tx * 4 + 2], b3 = Bs[hh][tx * 4 + 3];
            acc[0][0] += a0 * b0; acc[0][1] += a0 * b1; acc[0][2] += a0 * b2; acc[0][3] += a0 * b3;
            acc[1][0] += a1 * b0; acc[1][1] += a1 * b1; acc[1][2] += a1 * b2; acc[1][3] += a1 * b3;
            acc[2][0] += a2 * b0; acc[2][1] += a2 * b1; acc[2][2] += a2 * b2; acc[2][3] += a2 * b3;
            acc[3][0] += a3 * b0; acc[3][1] += a3 * b1; acc[3][2] += a3 * b2; acc[3][3] += a3 * b3;
        }
        __syncthreads();
    }
    if (threadIdx.x < 64) selred[threadIdx.x] = 0.f;
    __syncthreads();
#pragma unroll
    for (int i = 0; i < 4; ++i) {
        int t = t0 + ty * 4 + i;
        float sacc = 0.f;
#pragma unroll
        for (int j = 0; j < 4; ++j) {
            int k = k0 + tx * 4 + j;
            float vv = (k < 513) ? V[(size_t)t * 516 + k] : 0.f;
            sacc += acc[i][j] * vv;
        }
        atomicAdd(&selred[ty * 4 + i], sacc);
    }
    __syncthreads();
    if (threadIdx.x < 64)
        atomicAdd(&sel[(size_t)l * 512 + t0 + threadIdx.x], selred[threadIdx.x]);
}

// ---------------------------------------------------------------------------
// Row softmax in place (512 rows x 512 cols), one WG per row
// ---------------------------------------------------------------------------
__global__ __launch_bounds__(256) void softmax_rows(float* __restrict__ Smat) {
    __shared__ float sdata[256];
    int i = blockIdx.x, tid = threadIdx.x;
    float* row = Smat + (size_t)i * 512;
    float m = -1e30f;
    for (int j = tid; j < 512; j += 256) m = fmaxf(m, row[j]);
    sdata[tid] = m; __syncthreads();
    for (int off = 128; off > 0; off >>= 1) {
        if (tid < off) sdata[tid] = fmaxf(sdata[tid], sdata[tid + off]);
        __syncthreads();
    }
    m = sdata[0]; __syncthreads();
    float ssum = 0.f;
    for (int j = tid; j < 512; j += 256) { float e = __expf(row[j] - m); row[j] = e; ssum += e; }
    sdata[tid] = ssum; __syncthreads();
    for (int off = 128; off > 0; off >>= 1) {
        if (tid < off) sdata[tid] += sdata[tid + off];
        __syncthreads();
    }
    float inv = 1.f / sdata[0];
    for (int j = tid; j < 512; j += 256) row[j] *= inv;
}

// ---------------------------------------------------------------------------
// log_softmax over l (50) for each t (512): out1[l*512+t]
// ---------------------------------------------------------------------------
__global__ void lsm_k(const float* __restrict__ sel, float* __restrict__ out1) {
    int t = blockIdx.x * blockDim.x + threadIdx.x;
    if (t >= 512) return;
    float m = -1e30f;
    for (int l = 0; l < 50; ++l) m = fmaxf(m, sel[l * 512 + t]);
    float ssum = 0.f;
    for (int l = 0; l < 50; ++l) ssum += __expf(sel[l * 512 + t] - m);
    float lse = m + __logf(ssum);
    for (int l = 0; l < 50; ++l) out1[l * 512 + t] = sel[l * 512 + t] - lse;
}

// ---------------------------------------------------------------------------
extern "C" void kernel_launch(void* const* d_in, const int* in_sizes, int n_in,
                              void* d_out, int out_size, void* d_ws, size_t ws_size,
                              hipStream_t stream) {
    const int* sentence     = (const int*)d_in[0];
    const int* tags         = (const int*)d_in[1];
    const int* chars        = (const int*)d_in[2];
    const int* char_lengths = (const int*)d_in[3];
    const int* best_arcs    = (const int*)d_in[4];
    const float* word_emb   = (const float*)d_in[5];
    const float* tag_emb    = (const float*)d_in[6];
    const float* char_emb   = (const float*)d_in[7];
    const float* att_W      = (const float*)d_in[8];
    const float* att_b      = (const float*)d_in[9];
    const float* W_ih_f     = (const float*)d_in[10];
    const float* W_hh_f     = (const float*)d_in[11];
    const float* b_f        = (const float*)d_in[12];
    const float* W_ih_b     = (const float*)d_in[13];
    const float* W_hh_b     = (const float*)d_in[14];
    const float* b_b        = (const float*)d_in[15];
    const float* cW_ih      = (const float*)d_in[16];
    const float* cW_hh      = (const float*)d_in[17];
    const float* cb         = (const float*)d_in[18];
    const float* arc_dep_W  = (const float*)d_in[19];
    const float* arc_dep_b  = (const float*)d_in[20];
    const float* arc_head_W = (const float*)d_in[21];
    const float* arc_head_b = (const float*)d_in[22];
    const float* label_dep_W  = (const float*)d_in[23];
    const float* label_dep_b  = (const float*)d_in[24];
    const float* label_head_W = (const float*)d_in[25];
    const float* label_head_b = (const float*)d_in[26];
    const float* biaff_arc_W   = (const float*)d_in[27];
    const float* biaff_label_W = (const float*)d_in[28];

    float* ws = (float*)d_ws;
    float* out = (float*)d_out;

    // workspace layout (float offsets), total ~18.8 MB
    const size_t o_embeds = 0;        // 512*400
    const size_t o_xf     = 204800;   // 512*2048
    const size_t o_xb     = 1253376;  // 512*2048
    const size_t o_lstm   = 2301952;  // 512*1024
    const size_t o_heads  = 2826240;  // 4 * 512*512
    const size_t o_P      = 3874816;  // 512*512
    const size_t o_U      = 4136960;  // 512*516
    const size_t o_V      = 4401152;  // 512*516
    const size_t o_sel    = 4665344;  // 50*512
    const size_t o_hG     = 4690944;  // 2 dirs * 2 bufs * 512
    const size_t o_cnt    = 4692992;  // 2 counters, 128B apart

    // zero h ping-pong buffers + barrier counters + sel accumulator
    hipMemsetAsync(ws + o_hG, 0, (2048 + 64) * sizeof(float), stream);
    hipMemsetAsync(ws + o_sel, 0, 25600 * sizeof(float), stream);

    gather_k<<<512, 128, 0, stream>>>(sentence, tags, word_emb, tag_emb, ws + o_embeds);
    char_k<<<512, 64, 0, stream>>>(chars, char_lengths, char_emb, att_W, att_b,
                                   cW_ih, cW_hh, cb, out + 287744);

    // input projections (bias folded): xf[t] = embeds[t]@W_ih_f^T + b_f ; xb[t] = embeds[511-t]@W_ih_b^T + b_b
    gemm_abT<<<dim3(32, 8), 256, 0, stream>>>(ws + o_embeds, 400, W_ih_f, 400, b_f, 1,
                                              ws + o_xf, 2048, 512, 2048, 400, 0, 0);
    gemm_abT<<<dim3(32, 8), 256, 0, stream>>>(ws + o_embeds, 400, W_ih_b, 400, b_b, 1,
                                              ws + o_xb, 2048, 512, 2048, 400, 1, 0);

    lstm_rec<<<32, 256, 0, stream>>>(W_hh_f, W_hh_b, ws + o_xf, ws + o_xb,
                                     ws + o_lstm, ws + o_hG, (unsigned*)(ws + o_cnt));

    // 4 MLP heads: relu(lstm_out @ W^T + b)
    gemm_abT<<<dim3(8, 8), 256, 0, stream>>>(ws + o_lstm, 1024, arc_dep_W, 1024, arc_dep_b, 1,
                                             ws + o_heads + 0, 512, 512, 512, 1024, 0, 1);
    gemm_abT<<<dim3(8, 8), 256, 0, stream>>>(ws + o_lstm, 1024, arc_head_W, 1024, arc_head_b, 1,
                                             ws + o_heads + 262144, 512, 512, 512, 1024, 0, 1);
    gemm_abT<<<dim3(8, 8), 256, 0, stream>>>(ws + o_lstm, 1024, label_dep_W, 1024, label_dep_b, 1,
                                             ws + o_heads + 524288, 512, 512, 512, 1024, 0, 1);
    gemm_abT<<<dim3(8, 8), 256, 0, stream>>>(ws + o_lstm, 1024, label_head_W, 1024, label_head_b, 1,
                                             ws + o_heads + 786432, 512, 512, 512, 1024, 0, 1);

    uv_k<<<512, 128, 0, stream>>>(best_arcs, ws + o_heads + 786432, ws + o_heads + 524288,
                                  ws + o_U, ws + o_V);

    // P = arc_head_a @ biaff_arc_W^T : ones-column folded as bias = biaff_arc_W[:,512]
    gemm_abT<<<dim3(8, 8), 256, 0, stream>>>(ws + o_heads + 262144, 512, biaff_arc_W, 513,
                                             biaff_arc_W + 512, 513,
                                             ws + o_P, 512, 512, 512, 512, 0, 0);
    // S = P @ arc_dep^T  -> write to out0, then row-softmax in place
    gemm_abT<<<dim3(8, 8), 256, 0, stream>>>(ws + o_P, 512, ws + o_heads + 0, 512, nullptr, 0,
                                             out, 512, 512, 512, 512, 0, 0);
    softmax_rows<<<512, 256, 0, stream>>>(out);

    label_k<<<dim3(9, 8, 50), 256, 0, stream>>>(ws + o_U, ws + o_V, biaff_label_W, ws + o_sel);
    lsm_k<<<2, 256, 0, stream>>>(ws + o_sel, out + 262144);
}

// Round 2
// 2770.787 us; speedup vs baseline: 1.7306x; 1.7306x over previous
//
#include <hip/hip_runtime.h>
#include <hip/hip_fp16.h>

// ---------------------------------------------------------------------------
// Problem constants
//   S=512 tokens, WD=300, TD=100, CE=20, CH=20, H=512, LAB=50, MAXW=16
// Outputs: arc_scores (512x512) | label_scores (50x512) | char_embeds (20x512)
// ---------------------------------------------------------------------------

static __device__ __forceinline__ float sigm(float x) { return 1.f / (1.f + __expf(-x)); }
static __device__ __forceinline__ float ftanh(float x) {
    x = fminf(15.f, fmaxf(-15.f, x));
    float e = __expf(2.f * x);
    return (e - 1.f) / (e + 1.f);
}
static __device__ __forceinline__ unsigned f2bf(float x) {
    union { float f; unsigned u; } v; v.f = x;
    unsigned r = v.u + 0x7fffu + ((v.u >> 16) & 1u);
    return r >> 16;  // bf16 bits in low 16
}
static __device__ __forceinline__ float bflo(unsigned u) {
    union { unsigned u; float f; } v; v.u = u << 16; return v.f;
}
static __device__ __forceinline__ float bfhi(unsigned u) {
    union { unsigned u; float f; } v; v.u = u & 0xffff0000u; return v.f;
}

// ---------------------------------------------------------------------------
// Embedding gather: embeds[t][0:300]=word_emb[sentence[t]], [300:400]=tag_emb[tags[t]]
// ---------------------------------------------------------------------------
__global__ void gather_k(const int* __restrict__ sentence, const int* __restrict__ tags,
                         const float* __restrict__ word_emb, const float* __restrict__ tag_emb,
                         float* __restrict__ embeds) {
    int t = blockIdx.x;
    int w = sentence[t], tg = tags[t];
    for (int j = threadIdx.x; j < 400; j += blockDim.x) {
        float v = (j < 300) ? word_emb[w * 300 + j] : tag_emb[tg * 100 + (j - 300)];
        embeds[t * 400 + j] = v;
    }
}

// ---------------------------------------------------------------------------
// Generic fp32 GEMM: C[M,N] = A[M,K] @ B[N,K]^T (+ bias[n*bias_stride]) (opt relu)
// Requires M%64==0, N%64==0, K%16==0. revA: A rows read reversed.
// block 256 threads, 64x64 tile, 4x4 per thread.
// ---------------------------------------------------------------------------
__global__ __launch_bounds__(256) void gemm_abT(
    const float* __restrict__ A, int lda, const float* __restrict__ B, int ldb,
    const float* __restrict__ bias, int bias_stride,
    float* __restrict__ C, int ldc, int M, int N, int K, int revA, int doRelu) {
    __shared__ float As[16][65];
    __shared__ float Bs[16][65];
    int tx = threadIdx.x & 15, ty = threadIdx.x >> 4;
    int bm = blockIdx.y * 64, bn = blockIdx.x * 64;
    float acc[4][4] = {};
    for (int k0 = 0; k0 < K; k0 += 16) {
#pragma unroll
        for (int i = 0; i < 4; ++i) {
            int e = threadIdx.x + i * 256;   // 0..1023
            int m = e >> 4, kk = e & 15;
            int row = bm + m; if (revA) row = M - 1 - row;
            As[kk][m] = A[(size_t)row * lda + k0 + kk];
            Bs[kk][m] = B[(size_t)(bn + m) * ldb + k0 + kk];
        }
        __syncthreads();
#pragma unroll
        for (int kk = 0; kk < 16; ++kk) {
            float a0 = As[kk][ty * 4 + 0], a1 = As[kk][ty * 4 + 1];
            float a2 = As[kk][ty * 4 + 2], a3 = As[kk][ty * 4 + 3];
            float b0 = Bs[kk][tx * 4 + 0], b1 = Bs[kk][tx * 4 + 1];
            float b2 = Bs[kk][tx * 4 + 2], b3 = Bs[kk][tx * 4 + 3];
            acc[0][0] += a0 * b0; acc[0][1] += a0 * b1; acc[0][2] += a0 * b2; acc[0][3] += a0 * b3;
            acc[1][0] += a1 * b0; acc[1][1] += a1 * b1; acc[1][2] += a1 * b2; acc[1][3] += a1 * b3;
            acc[2][0] += a2 * b0; acc[2][1] += a2 * b1; acc[2][2] += a2 * b2; acc[2][3] += a2 * b3;
            acc[3][0] += a3 * b0; acc[3][1] += a3 * b1; acc[3][2] += a3 * b2; acc[3][3] += a3 * b3;
        }
        __syncthreads();
    }
#pragma unroll
    for (int i = 0; i < 4; ++i) {
#pragma unroll
        for (int j = 0; j < 4; ++j) {
            int n = bn + tx * 4 + j;
            float v = acc[i][j];
            if (bias) v += bias[(size_t)n * bias_stride];
            if (doRelu) v = fmaxf(v, 0.f);
            C[(size_t)(bm + ty * 4 + i) * ldc + n] = v;
        }
    }
}

// ---------------------------------------------------------------------------
// Recurrent bidirectional LSTM. 32 WGs: dir = wg>>4, slice s = wg&15.
// Each WG owns h-dims [s*32, s*32+32) => 128 rows of W_hh in VGPRs (bf16 pairs).
//
// Cross-WG h exchange is FENCE-FREE: each pair of adjacent h columns is packed
// as (fp16(h) | tag<<16) x2 into one 8-byte relaxed agent-scope atomic word.
// Tag==step makes data+flag inseparable (single-word atomicity), so no
// release/acquire, no threadfence, no counter barrier. Ping-pong parity gives
// back-pressure: slot for step t+2 is only written after its producer consumed
// ALL of step t+1, which certifies every WG consumed step t.
// ---------------------------------------------------------------------------
__global__ __launch_bounds__(256) void lstm_rec(
    const float* __restrict__ W_hh_f, const float* __restrict__ W_hh_b,
    const float* __restrict__ xpf, const float* __restrict__ xpb,
    float* __restrict__ lstm_out, unsigned long long* hq) {
    int wg = blockIdx.x;
    int dir = wg >> 4, s = wg & 15;
    int tid = threadIdx.x;
    int g = tid & 31, p = tid >> 5;
    const float* Whh = dir ? W_hh_b : W_hh_f;
    const float* xp = dir ? xpb : xpf;

    __shared__ float hsh[512];
    __shared__ float red[8 * 128];  // [p][g][q]

    unsigned Wreg[4][32];
#pragma unroll
    for (int q = 0; q < 4; ++q) {
        int gr = q * 512 + s * 32 + g;
        const float* wrow = Whh + (size_t)gr * 512 + p * 64;
#pragma unroll
        for (int u = 0; u < 32; ++u) {
            unsigned lo = f2bf(wrow[2 * u]);
            unsigned hi = f2bf(wrow[2 * u + 1]);
            Wreg[q][u] = lo | (hi << 16);
        }
    }

    float c = 0.f;
    unsigned long long* hbase = hq + dir * 512;  // 2 ping-pong buffers of 256 qwords

    for (int t = 0; t < 512; ++t) {
        // ---- acquire h(t): poll my qword (2 columns) until tag == t ----
        unsigned long long* hin = hbase + (t & 1) * 256;
        unsigned tag = (unsigned)t & 0xffffu;
        unsigned long long v;
        do {
            v = __hip_atomic_load(hin + tid, __ATOMIC_RELAXED, __HIP_MEMORY_SCOPE_AGENT);
        } while ((((unsigned)(v >> 16)) & 0xffffu) != tag || ((unsigned)(v >> 48)) != tag);
        {
            __half_raw h0r, h1r;
            h0r.x = (unsigned short)(v & 0xffffu);
            h1r.x = (unsigned short)((v >> 32) & 0xffffu);
            hsh[2 * tid]     = __half2float(__half(h0r));
            hsh[2 * tid + 1] = __half2float(__half(h1r));
        }
        __syncthreads();

        // ---- matvec: my 128 rows x 512 cols ----
        float a0 = 0.f, a1 = 0.f, a2 = 0.f, a3 = 0.f;
        const float* hv = hsh + p * 64;
#pragma unroll
        for (int u = 0; u < 32; ++u) {
            float h0 = hv[2 * u], h1 = hv[2 * u + 1];
            unsigned w0 = Wreg[0][u]; a0 += bflo(w0) * h0; a0 += bfhi(w0) * h1;
            unsigned w1 = Wreg[1][u]; a1 += bflo(w1) * h0; a1 += bfhi(w1) * h1;
            unsigned w2 = Wreg[2][u]; a2 += bflo(w2) * h0; a2 += bfhi(w2) * h1;
            unsigned w3 = Wreg[3][u]; a3 += bflo(w3) * h0; a3 += bfhi(w3) * h1;
        }
        float* r = red + p * 128 + g * 4;
        r[0] = a0; r[1] = a1; r[2] = a2; r[3] = a3;
        __syncthreads();

        // ---- reduce over p, gates, publish h(t+1) ----
        if (tid < 32) {
            float z0 = 0.f, z1 = 0.f, z2 = 0.f, z3 = 0.f;
#pragma unroll
            for (int pp = 0; pp < 8; ++pp) {
                const float* rr = red + pp * 128 + tid * 4;
                z0 += rr[0]; z1 += rr[1]; z2 += rr[2]; z3 += rr[3];
            }
            int col = s * 32 + tid;
            const float* x = xp + (size_t)t * 2048;
            z0 += x[col];          // i
            z1 += x[512 + col];    // f
            z2 += x[1024 + col];   // g
            z3 += x[1536 + col];   // o
            c = sigm(z1) * c + sigm(z0) * ftanh(z2);
            float hn = sigm(z3) * ftanh(c);
            int row = dir ? (511 - t) : t;
            lstm_out[(size_t)row * 1024 + dir * 512 + col] = hn;

            // pack fp16(h) | tag(t+1)<<16 ; pair two adjacent cols into 8B
            unsigned short hb = __half_as_ushort(__float2half(hn));
            unsigned tw = (unsigned)hb | (((unsigned)(t + 1) & 0xffffu) << 16);
            unsigned other = (unsigned)__shfl_down((int)tw, 1);
            if ((tid & 1) == 0) {
                unsigned long long qv = (unsigned long long)tw |
                                        ((unsigned long long)other << 32);
                __hip_atomic_store(hbase + ((t + 1) & 1) * 256 + (col >> 1), qv,
                                   __ATOMIC_RELAXED, __HIP_MEMORY_SCOPE_AGENT);
            }
        }
        __syncthreads();  // protect hsh/red reuse next iteration
    }
}

// ---------------------------------------------------------------------------
// Per-word char LSTM + masked gram attention.
// out[e][w] = sum_{t<L} h_t[e] * (h_t . attW) + att_b   (h_t from full 16-step scan)
// One 64-thread WG per word; lanes 0..19 = h dims.
// ---------------------------------------------------------------------------
__global__ __launch_bounds__(64) void char_k(
    const int* __restrict__ chars, const int* __restrict__ char_lengths,
    const float* __restrict__ char_emb, const float* __restrict__ att_W,
    const float* __restrict__ att_b, const float* __restrict__ cW_ih,
    const float* __restrict__ cW_hh, const float* __restrict__ cb,
    float* __restrict__ out2) {
    int w = blockIdx.x, tid = threadIdx.x;
    __shared__ float Wih[1600], Whh[1600], cbs[80], attsh[20];
    __shared__ float xsh[20], hsh[20], prodsh[20];
    for (int i = tid; i < 1600; i += 64) { Wih[i] = cW_ih[i]; Whh[i] = cW_hh[i]; }
    for (int i = tid; i < 80; i += 64) cbs[i] = cb[i];
    if (tid < 20) { attsh[tid] = att_W[tid]; hsh[tid] = 0.f; }
    __syncthreads();

    int L = char_lengths[w];
    float c = 0.f, accj = 0.f;
    for (int t = 0; t < 16; ++t) {
        if (tid < 20) xsh[tid] = char_emb[(size_t)chars[w * 16 + t] * 20 + tid];
        __syncthreads();
        float hn = 0.f;
        if (tid < 20) {
            float z[4];
#pragma unroll
            for (int q = 0; q < 4; ++q) {
                int r = q * 20 + tid;
                float sacc = cbs[r];
                for (int d = 0; d < 20; ++d)
                    sacc += Wih[r * 20 + d] * xsh[d] + Whh[r * 20 + d] * hsh[d];
                z[q] = sacc;
            }
            c = sigm(z[1]) * c + sigm(z[0]) * ftanh(z[2]);
            hn = sigm(z[3]) * ftanh(c);
        }
        __syncthreads();
        if (tid < 20) { hsh[tid] = hn; prodsh[tid] = hn * attsh[tid]; }
        __syncthreads();
        if (tid < 20 && t < L) {
            float st = 0.f;
            for (int k = 0; k < 20; ++k) st += prodsh[k];
            accj += hn * st;
        }
        __syncthreads();
    }
    if (tid < 20) out2[tid * 512 + w] = accj + att_b[0];
}

// ---------------------------------------------------------------------------
// Build U[t] = [label_head[best_arcs[t]], 1, 0, 0, 0], V[t] = [label_dep[t], 1, 0,0,0]
// (row stride 516, zero-padded past col 512)
// ---------------------------------------------------------------------------
__global__ void uv_k(const int* __restrict__ best_arcs,
                     const float* __restrict__ label_head, const float* __restrict__ label_dep,
                     float* __restrict__ U, float* __restrict__ V) {
    int t = blockIdx.x;
    int ba = best_arcs[t];
    for (int j = threadIdx.x; j < 516; j += blockDim.x) {
        float u = (j < 512) ? label_head[(size_t)ba * 512 + j] : (j == 512 ? 1.f : 0.f);
        float v = (j < 512) ? label_dep[(size_t)t * 512 + j] : (j == 512 ? 1.f : 0.f);
        U[t * 516 + j] = u;
        V[t * 516 + j] = v;
    }
}

// ---------------------------------------------------------------------------
// Label biaffine: sel[l,t] += sum_{k-tile} (U[t,:] @ B_l[:, ktile]) . V[t, ktile]
// grid (ktile=9, ttile=8, l=50), block 256, 64x64 D-tile, 4x4/thread.
// ---------------------------------------------------------------------------
__global__ __launch_bounds__(256) void label_k(
    const float* __restrict__ U, const float* __restrict__ V,
    const float* __restrict__ BW, float* __restrict__ sel) {
    __shared__ float Us[16][65];
    __shared__ float Bs[16][65];
    __shared__ float selred[64];
    int l = blockIdx.z;
    int t0 = blockIdx.y * 64, k0 = blockIdx.x * 64;
    const float* Bl = BW + (size_t)l * 513 * 513;
    int tx = threadIdx.x & 15, ty = threadIdx.x >> 4;
    float acc[4][4] = {};
    for (int h0 = 0; h0 < 513; h0 += 16) {
#pragma unroll
        for (int i = 0; i < 4; ++i) {
            int e = threadIdx.x + i * 256;
            int a = e >> 4, hh = e & 15;
            int h = h0 + hh;
            Us[hh][a] = (h < 513) ? U[(size_t)(t0 + a) * 516 + h] : 0.f;
            int kc = k0 + a;
            Bs[hh][a] = (h < 513 && kc < 513) ? Bl[(size_t)h * 513 + kc] : 0.f;
        }
        __syncthreads();
#pragma unroll
        for (int hh = 0; hh < 16; ++hh) {
            float a0 = Us[hh][ty * 4 + 0], a1 = Us[hh][ty * 4 + 1];
            float a2 = Us[hh][ty * 4 + 2], a3 = Us[hh][ty * 4 + 3];
            float b0 = Bs[hh][tx * 4 + 0], b1 = Bs[hh][tx * 4 + 1];
            float b2 = Bs[hh][tx * 4 + 2], b3 = Bs[hh][tx * 4 + 3];
            acc[0][0] += a0 * b0; acc[0][1] += a0 * b1; acc[0][2] += a0 * b2; acc[0][3] += a0 * b3;
            acc[1][0] += a1 * b0; acc[1][1] += a1 * b1; acc[1][2] += a1 * b2; acc[1][3] += a1 * b3;
            acc[2][0] += a2 * b0; acc[2][1] += a2 * b1; acc[2][2] += a2 * b2; acc[2][3] += a2 * b3;
            acc[3][0] += a3 * b0; acc[3][1] += a3 * b1; acc[3][2] += a3 * b2; acc[3][3] += a3 * b3;
        }
        __syncthreads();
    }
    if (threadIdx.x < 64) selred[threadIdx.x] = 0.f;
    __syncthreads();
#pragma unroll
    for (int i = 0; i < 4; ++i) {
        int t = t0 + ty * 4 + i;
        float sacc = 0.f;
#pragma unroll
        for (int j = 0; j < 4; ++j) {
            int k = k0 + tx * 4 + j;
            float vv = (k < 513) ? V[(size_t)t * 516 + k] : 0.f;
            sacc += acc[i][j] * vv;
        }
        atomicAdd(&selred[ty * 4 + i], sacc);
    }
    __syncthreads();
    if (threadIdx.x < 64)
        atomicAdd(&sel[(size_t)l * 512 + t0 + threadIdx.x], selred[threadIdx.x]);
}

// ---------------------------------------------------------------------------
// Row softmax in place (512 rows x 512 cols), one WG per row
// ---------------------------------------------------------------------------
__global__ __launch_bounds__(256) void softmax_rows(float* __restrict__ Smat) {
    __shared__ float sdata[256];
    int i = blockIdx.x, tid = threadIdx.x;
    float* row = Smat + (size_t)i * 512;
    float m = -1e30f;
    for (int j = tid; j < 512; j += 256) m = fmaxf(m, row[j]);
    sdata[tid] = m; __syncthreads();
    for (int off = 128; off > 0; off >>= 1) {
        if (tid < off) sdata[tid] = fmaxf(sdata[tid], sdata[tid + off]);
        __syncthreads();
    }
    m = sdata[0]; __syncthreads();
    float ssum = 0.f;
    for (int j = tid; j < 512; j += 256) { float e = __expf(row[j] - m); row[j] = e; ssum += e; }
    sdata[tid] = ssum; __syncthreads();
    for (int off = 128; off > 0; off >>= 1) {
        if (tid < off) sdata[tid] += sdata[tid + off];
        __syncthreads();
    }
    float inv = 1.f / sdata[0];
    for (int j = tid; j < 512; j += 256) row[j] *= inv;
}

// ---------------------------------------------------------------------------
// log_softmax over l (50) for each t (512): out1[l*512+t]
// ---------------------------------------------------------------------------
__global__ void lsm_k(const float* __restrict__ sel, float* __restrict__ out1) {
    int t = blockIdx.x * blockDim.x + threadIdx.x;
    if (t >= 512) return;
    float m = -1e30f;
    for (int l = 0; l < 50; ++l) m = fmaxf(m, sel[l * 512 + t]);
    float ssum = 0.f;
    for (int l = 0; l < 50; ++l) ssum += __expf(sel[l * 512 + t] - m);
    float lse = m + __logf(ssum);
    for (int l = 0; l < 50; ++l) out1[l * 512 + t] = sel[l * 512 + t] - lse;
}

// ---------------------------------------------------------------------------
extern "C" void kernel_launch(void* const* d_in, const int* in_sizes, int n_in,
                              void* d_out, int out_size, void* d_ws, size_t ws_size,
                              hipStream_t stream) {
    const int* sentence     = (const int*)d_in[0];
    const int* tags         = (const int*)d_in[1];
    const int* chars        = (const int*)d_in[2];
    const int* char_lengths = (const int*)d_in[3];
    const int* best_arcs    = (const int*)d_in[4];
    const float* word_emb   = (const float*)d_in[5];
    const float* tag_emb    = (const float*)d_in[6];
    const float* char_emb   = (const float*)d_in[7];
    const float* att_W      = (const float*)d_in[8];
    const float* att_b      = (const float*)d_in[9];
    const float* W_ih_f     = (const float*)d_in[10];
    const float* W_hh_f     = (const float*)d_in[11];
    const float* b_f        = (const float*)d_in[12];
    const float* W_ih_b     = (const float*)d_in[13];
    const float* W_hh_b     = (const float*)d_in[14];
    const float* b_b        = (const float*)d_in[15];
    const float* cW_ih      = (const float*)d_in[16];
    const float* cW_hh      = (const float*)d_in[17];
    const float* cb         = (const float*)d_in[18];
    const float* arc_dep_W  = (const float*)d_in[19];
    const float* arc_dep_b  = (const float*)d_in[20];
    const float* arc_head_W = (const float*)d_in[21];
    const float* arc_head_b = (const float*)d_in[22];
    const float* label_dep_W  = (const float*)d_in[23];
    const float* label_dep_b  = (const float*)d_in[24];
    const float* label_head_W = (const float*)d_in[25];
    const float* label_head_b = (const float*)d_in[26];
    const float* biaff_arc_W   = (const float*)d_in[27];
    const float* biaff_label_W = (const float*)d_in[28];

    float* ws = (float*)d_ws;
    float* out = (float*)d_out;

    // workspace layout (float offsets), total ~18.8 MB
    const size_t o_embeds = 0;        // 512*400
    const size_t o_xf     = 204800;   // 512*2048
    const size_t o_xb     = 1253376;  // 512*2048
    const size_t o_lstm   = 2301952;  // 512*1024
    const size_t o_heads  = 2826240;  // 4 * 512*512
    const size_t o_P      = 3874816;  // 512*512
    const size_t o_U      = 4136960;  // 512*516
    const size_t o_V      = 4401152;  // 512*516
    const size_t o_sel    = 4665344;  // 50*512
    const size_t o_hG     = 4690944;  // 2 dirs * 2 parity bufs * 256 qwords = 8 KB

    // zero h exchange buffers (value=0, tag=0 == initial state) + sel accumulator
    hipMemsetAsync(ws + o_hG, 0, 2048 * sizeof(unsigned long long) / 2, stream); // 8 KB
    hipMemsetAsync(ws + o_sel, 0, 25600 * sizeof(float), stream);

    gather_k<<<512, 128, 0, stream>>>(sentence, tags, word_emb, tag_emb, ws + o_embeds);
    char_k<<<512, 64, 0, stream>>>(chars, char_lengths, char_emb, att_W, att_b,
                                   cW_ih, cW_hh, cb, out + 287744);

    // input projections (bias folded): xf[t] = embeds[t]@W_ih_f^T + b_f ; xb[t] = embeds[511-t]@W_ih_b^T + b_b
    gemm_abT<<<dim3(32, 8), 256, 0, stream>>>(ws + o_embeds, 400, W_ih_f, 400, b_f, 1,
                                              ws + o_xf, 2048, 512, 2048, 400, 0, 0);
    gemm_abT<<<dim3(32, 8), 256, 0, stream>>>(ws + o_embeds, 400, W_ih_b, 400, b_b, 1,
                                              ws + o_xb, 2048, 512, 2048, 400, 1, 0);

    lstm_rec<<<32, 256, 0, stream>>>(W_hh_f, W_hh_b, ws + o_xf, ws + o_xb,
                                     ws + o_lstm, (unsigned long long*)(ws + o_hG));

    // 4 MLP heads: relu(lstm_out @ W^T + b)
    gemm_abT<<<dim3(8, 8), 256, 0, stream>>>(ws + o_lstm, 1024, arc_dep_W, 1024, arc_dep_b, 1,
                                             ws + o_heads + 0, 512, 512, 512, 1024, 0, 1);
    gemm_abT<<<dim3(8, 8), 256, 0, stream>>>(ws + o_lstm, 1024, arc_head_W, 1024, arc_head_b, 1,
                                             ws + o_heads + 262144, 512, 512, 512, 1024, 0, 1);
    gemm_abT<<<dim3(8, 8), 256, 0, stream>>>(ws + o_lstm, 1024, label_dep_W, 1024, label_dep_b, 1,
                                             ws + o_heads + 524288, 512, 512, 512, 1024, 0, 1);
    gemm_abT<<<dim3(8, 8), 256, 0, stream>>>(ws + o_lstm, 1024, label_head_W, 1024, label_head_b, 1,
                                             ws + o_heads + 786432, 512, 512, 512, 1024, 0, 1);

    uv_k<<<512, 128, 0, stream>>>(best_arcs, ws + o_heads + 786432, ws + o_heads + 524288,
                                  ws + o_U, ws + o_V);

    // P = arc_head_a @ biaff_arc_W^T : ones-column folded as bias = biaff_arc_W[:,512]
    gemm_abT<<<dim3(8, 8), 256, 0, stream>>>(ws + o_heads + 262144, 512, biaff_arc_W, 513,
                                             biaff_arc_W + 512, 513,
                                             ws + o_P, 512, 512, 512, 512, 0, 0);
    // S = P @ arc_dep^T  -> write to out0, then row-softmax in place
    gemm_abT<<<dim3(8, 8), 256, 0, stream>>>(ws + o_P, 512, ws + o_heads + 0, 512, nullptr, 0,
                                             out, 512, 512, 512, 512, 0, 0);
    softmax_rows<<<512, 256, 0, stream>>>(out);

    label_k<<<dim3(9, 8, 50), 256, 0, stream>>>(ws + o_U, ws + o_V, biaff_label_W, ws + o_sel);
    lsm_k<<<2, 256, 0, stream>>>(ws + o_sel, out + 262144);
}

// Round 3
// 1859.733 us; speedup vs baseline: 2.5783x; 1.4899x over previous
//
#include <hip/hip_runtime.h>
#include <hip/hip_fp16.h>

// ---------------------------------------------------------------------------
// Problem constants
//   S=512 tokens, WD=300, TD=100, CE=20, CH=20, H=512, LAB=50, MAXW=16
// Outputs: arc_scores (512x512) | label_scores (50x512) | char_embeds (20x512)
// ---------------------------------------------------------------------------

static __device__ __forceinline__ float sigm(float x) { return 1.f / (1.f + __expf(-x)); }
static __device__ __forceinline__ float ftanh(float x) {
    x = fminf(15.f, fmaxf(-15.f, x));
    float e = __expf(2.f * x);
    return (e - 1.f) / (e + 1.f);
}

typedef _Float16 h2_t __attribute__((ext_vector_type(2)));
union U32H2 { unsigned u; h2_t h; unsigned short s[2]; };

static __device__ __forceinline__ float dot2f(unsigned wa, unsigned hb, float c) {
#if __has_builtin(__builtin_amdgcn_fdot2)
    U32H2 a, b; a.u = wa; b.u = hb;
    return __builtin_amdgcn_fdot2(a.h, b.h, c, false);
#else
    U32H2 a, b; a.u = wa; b.u = hb;
    return c + (float)a.h[0] * (float)b.h[0] + (float)a.h[1] * (float)b.h[1];
#endif
}
static __device__ __forceinline__ unsigned short f2h16(float x) {
    return __half_as_ushort(__float2half(x));
}

// ---------------------------------------------------------------------------
// Embedding gather
// ---------------------------------------------------------------------------
__global__ void gather_k(const int* __restrict__ sentence, const int* __restrict__ tags,
                         const float* __restrict__ word_emb, const float* __restrict__ tag_emb,
                         float* __restrict__ embeds) {
    int t = blockIdx.x;
    int w = sentence[t], tg = tags[t];
    for (int j = threadIdx.x; j < 400; j += blockDim.x) {
        float v = (j < 300) ? word_emb[w * 300 + j] : tag_emb[tg * 100 + (j - 300)];
        embeds[t * 400 + j] = v;
    }
}

// ---------------------------------------------------------------------------
// Shared fp32 GEMM tile body: C[64x64 tile] = A[M,K] @ B[N,K]^T (+bias)(relu)
// ---------------------------------------------------------------------------
static __device__ __forceinline__ void gemm_body(
    const float* __restrict__ A, int lda, const float* __restrict__ B, int ldb,
    const float* __restrict__ bias, int bias_stride,
    float* __restrict__ C, int ldc, int M, int K, int revA, int doRelu) {
    __shared__ float As[16][65];
    __shared__ float Bs[16][65];
    int tx = threadIdx.x & 15, ty = threadIdx.x >> 4;
    int bm = blockIdx.y * 64, bn = blockIdx.x * 64;
    float acc[4][4] = {};
    for (int k0 = 0; k0 < K; k0 += 16) {
#pragma unroll
        for (int i = 0; i < 4; ++i) {
            int e = threadIdx.x + i * 256;
            int m = e >> 4, kk = e & 15;
            int row = bm + m; if (revA) row = M - 1 - row;
            As[kk][m] = A[(size_t)row * lda + k0 + kk];
            Bs[kk][m] = B[(size_t)(bn + m) * ldb + k0 + kk];
        }
        __syncthreads();
#pragma unroll
        for (int kk = 0; kk < 16; ++kk) {
            float a0 = As[kk][ty * 4 + 0], a1 = As[kk][ty * 4 + 1];
            float a2 = As[kk][ty * 4 + 2], a3 = As[kk][ty * 4 + 3];
            float b0 = Bs[kk][tx * 4 + 0], b1 = Bs[kk][tx * 4 + 1];
            float b2 = Bs[kk][tx * 4 + 2], b3 = Bs[kk][tx * 4 + 3];
            acc[0][0] += a0 * b0; acc[0][1] += a0 * b1; acc[0][2] += a0 * b2; acc[0][3] += a0 * b3;
            acc[1][0] += a1 * b0; acc[1][1] += a1 * b1; acc[1][2] += a1 * b2; acc[1][3] += a1 * b3;
            acc[2][0] += a2 * b0; acc[2][1] += a2 * b1; acc[2][2] += a2 * b2; acc[2][3] += a2 * b3;
            acc[3][0] += a3 * b0; acc[3][1] += a3 * b1; acc[3][2] += a3 * b2; acc[3][3] += a3 * b3;
        }
        __syncthreads();
    }
#pragma unroll
    for (int i = 0; i < 4; ++i) {
#pragma unroll
        for (int j = 0; j < 4; ++j) {
            int n = bn + tx * 4 + j;
            float v = acc[i][j];
            if (bias) v += bias[(size_t)n * bias_stride];
            if (doRelu) v = fmaxf(v, 0.f);
            C[(size_t)(bm + ty * 4 + i) * ldc + n] = v;
        }
    }
}

__global__ __launch_bounds__(256) void gemm_abT(
    const float* __restrict__ A, int lda, const float* __restrict__ B, int ldb,
    const float* __restrict__ bias, int bias_stride,
    float* __restrict__ C, int ldc, int M, int N, int K, int revA, int doRelu) {
    gemm_body(A, lda, B, ldb, bias, bias_stride, C, ldc, M, K, revA, doRelu);
}

// 4 MLP heads fused on grid.z: relu(lstm_out @ W^T + b), M=N=512, K=1024
__global__ __launch_bounds__(256) void gemm_heads(
    const float* __restrict__ A,
    const float* W0, const float* B0, float* C0,
    const float* W1, const float* B1, float* C1,
    const float* W2, const float* B2, float* C2,
    const float* W3, const float* B3, float* C3) {
    const float* W; const float* bias; float* C;
    switch (blockIdx.z) {
        case 0: W = W0; bias = B0; C = C0; break;
        case 1: W = W1; bias = B1; C = C1; break;
        case 2: W = W2; bias = B2; C = C2; break;
        default: W = W3; bias = B3; C = C3; break;
    }
    gemm_body(A, 1024, W, 1024, bias, 1, C, 512, 512, 1024, 0, 1);
}

// 2 input projections fused on grid.z (z=1 reverses A rows), M=512,N=2048,K=400
__global__ __launch_bounds__(256) void gemm_xproj(
    const float* __restrict__ A,
    const float* Wf, const float* bf, float* Cf,
    const float* Wb, const float* bb, float* Cb) {
    const float* W = blockIdx.z ? Wb : Wf;
    const float* bias = blockIdx.z ? bb : bf;
    float* C = blockIdx.z ? Cb : Cf;
    gemm_body(A, 400, W, 400, bias, 1, C, 2048, 512, 400, blockIdx.z, 0);
}

// ---------------------------------------------------------------------------
// Recurrent bidirectional LSTM. 32 WGs: dir = wg>>4, slice s = wg&15.
// Protocol (proven in r2): h exchanged as (fp16|tag)x2 packed in one 8-byte
// relaxed agent-scope atomic qword; parity ping-pong gives back-pressure.
// r3 changes: (1) each WAVE polls only its own 64 qwords (1/lane, predicated
// retry) and distributes intra-wave via __shfl -- no staging LDS, no staging
// barrier; (2) single __syncthreads per step (red ping-pong on t&1 removes
// the WAR barrier: red[par] readers must pass barrier t+1 before rewrite at
// t+2); (3) fp16 weights + v_dot2_f32_f16 matvec; (4) x loads preissued.
// ---------------------------------------------------------------------------
__global__ __launch_bounds__(256) void lstm_rec(
    const float* __restrict__ W_hh_f, const float* __restrict__ W_hh_b,
    const float* __restrict__ xpf, const float* __restrict__ xpb,
    float* __restrict__ lstm_out, unsigned long long* hq) {
    int wg = blockIdx.x;
    int dir = wg >> 4, s = wg & 15;
    int tid = threadIdx.x;
    int wv = tid >> 6;          // wave 0..3
    int lane = tid & 63;
    int g = tid & 31, p = tid >> 5;   // p in [0,8): 64-col block
    const float* Whh = dir ? W_hh_b : W_hh_f;
    const float* xp = dir ? xpb : xpf;

    __shared__ float red[2][1024];   // ping-pong [par][p*128 + g*4 + q]

    // Weights: thread (g,p) owns rows {q*512 + s*32 + g}, cols [p*64,p*64+64)
    // packed as 32 fp16-pairs per gate.
    unsigned Wreg[4][32];
#pragma unroll
    for (int q = 0; q < 4; ++q) {
        int gr = q * 512 + s * 32 + g;
        const float* wrow = Whh + (size_t)gr * 512 + p * 64;
#pragma unroll
        for (int u = 0; u < 32; ++u) {
            unsigned lo = f2h16(wrow[2 * u]);
            unsigned hi = f2h16(wrow[2 * u + 1]);
            Wreg[q][u] = lo | (hi << 16);
        }
    }

    float c = 0.f;
    unsigned long long* hbase = hq + dir * 512;  // 2 parity buffers x 256 qwords
    int qidx = wv * 64 + lane;                   // this lane's polled qword

    for (int t = 0; t < 512; ++t) {
        // preissue x-projection loads for the gate lanes (independent of h)
        float x0 = 0.f, x1 = 0.f, x2 = 0.f, x3 = 0.f;
        if (tid < 32) {
            const float* x = xp + (size_t)t * 2048;
            int col = s * 32 + tid;
            x0 = x[col]; x1 = x[512 + col]; x2 = x[1024 + col]; x3 = x[1536 + col];
        }

        // ---- poll my qword (cols 2*qidx, 2*qidx+1) until tag==t ----
        unsigned long long* hin = hbase + (t & 1) * 256;
        unsigned tag = (unsigned)t & 0xffffu;
        unsigned long long v = __hip_atomic_load(hin + qidx, __ATOMIC_RELAXED,
                                                 __HIP_MEMORY_SCOPE_AGENT);
        while ((((unsigned)(v >> 16)) & 0xffffu) != tag || ((unsigned)(v >> 48)) != tag)
            v = __hip_atomic_load(hin + qidx, __ATOMIC_RELAXED, __HIP_MEMORY_SCOPE_AGENT);
        // repack to v2f16 (even col in lo16, odd col in hi16)
        unsigned hw = (unsigned)(v & 0xffffu) | (((unsigned)((v >> 32) & 0xffffu)) << 16);

        // ---- matvec via intra-wave shuffle; lane needs words of its p-half ----
        float a0 = 0.f, a1 = 0.f, a2 = 0.f, a3 = 0.f;
        int half_base = lane & 32;   // lower half-wave: words 0..31, upper: 32..63
#pragma unroll
        for (int u = 0; u < 32; ++u) {
            unsigned hwu = (unsigned)__shfl((int)hw, half_base + u);
            a0 = dot2f(Wreg[0][u], hwu, a0);
            a1 = dot2f(Wreg[1][u], hwu, a1);
            a2 = dot2f(Wreg[2][u], hwu, a2);
            a3 = dot2f(Wreg[3][u], hwu, a3);
        }
        float* r = &red[t & 1][p * 128 + g * 4];
        r[0] = a0; r[1] = a1; r[2] = a2; r[3] = a3;
        __syncthreads();   // the ONLY barrier this step

        // ---- reduce over p, gates, publish h(t+1) ----
        if (tid < 32) {
            float z0 = 0.f, z1 = 0.f, z2 = 0.f, z3 = 0.f;
            const float* rb = red[t & 1];
#pragma unroll
            for (int pp = 0; pp < 8; ++pp) {
                const float* rr = rb + pp * 128 + tid * 4;
                z0 += rr[0]; z1 += rr[1]; z2 += rr[2]; z3 += rr[3];
            }
            z0 += x0; z1 += x1; z2 += x2; z3 += x3;
            c = sigm(z1) * c + sigm(z0) * ftanh(z2);
            float hn = sigm(z3) * ftanh(c);
            int col = s * 32 + tid;
            int row = dir ? (511 - t) : t;
            lstm_out[(size_t)row * 1024 + dir * 512 + col] = hn;

            unsigned tw = (unsigned)f2h16(hn) | (((unsigned)(t + 1) & 0xffffu) << 16);
            unsigned other = (unsigned)__shfl_down((int)tw, 1);
            if ((tid & 1) == 0) {
                unsigned long long qv = (unsigned long long)tw |
                                        ((unsigned long long)other << 32);
                __hip_atomic_store(hbase + ((t + 1) & 1) * 256 + (col >> 1), qv,
                                   __ATOMIC_RELAXED, __HIP_MEMORY_SCOPE_AGENT);
            }
        }
        // no trailing barrier: red is parity ping-ponged
    }
}

// ---------------------------------------------------------------------------
// Per-word char LSTM + masked gram attention (one 64-thread WG per word)
// ---------------------------------------------------------------------------
__global__ __launch_bounds__(64) void char_k(
    const int* __restrict__ chars, const int* __restrict__ char_lengths,
    const float* __restrict__ char_emb, const float* __restrict__ att_W,
    const float* __restrict__ att_b, const float* __restrict__ cW_ih,
    const float* __restrict__ cW_hh, const float* __restrict__ cb,
    float* __restrict__ out2) {
    int w = blockIdx.x, tid = threadIdx.x;
    __shared__ float Wih[1600], Whh[1600], cbs[80], attsh[20];
    __shared__ float xsh[20], hsh[20], prodsh[20];
    for (int i = tid; i < 1600; i += 64) { Wih[i] = cW_ih[i]; Whh[i] = cW_hh[i]; }
    for (int i = tid; i < 80; i += 64) cbs[i] = cb[i];
    if (tid < 20) { attsh[tid] = att_W[tid]; hsh[tid] = 0.f; }
    __syncthreads();

    int L = char_lengths[w];
    float c = 0.f, accj = 0.f;
    for (int t = 0; t < 16; ++t) {
        if (tid < 20) xsh[tid] = char_emb[(size_t)chars[w * 16 + t] * 20 + tid];
        __syncthreads();
        float hn = 0.f;
        if (tid < 20) {
            float z[4];
#pragma unroll
            for (int q = 0; q < 4; ++q) {
                int r = q * 20 + tid;
                float sacc = cbs[r];
                for (int d = 0; d < 20; ++d)
                    sacc += Wih[r * 20 + d] * xsh[d] + Whh[r * 20 + d] * hsh[d];
                z[q] = sacc;
            }
            c = sigm(z[1]) * c + sigm(z[0]) * ftanh(z[2]);
            hn = sigm(z[3]) * ftanh(c);
        }
        __syncthreads();
        if (tid < 20) { hsh[tid] = hn; prodsh[tid] = hn * attsh[tid]; }
        __syncthreads();
        if (tid < 20 && t < L) {
            float st = 0.f;
            for (int k = 0; k < 20; ++k) st += prodsh[k];
            accj += hn * st;
        }
        __syncthreads();
    }
    if (tid < 20) out2[tid * 512 + w] = accj + att_b[0];
}

// ---------------------------------------------------------------------------
// Build U[t] = [label_head[best_arcs[t]], 1, pad0], V[t] = [label_dep[t], 1, pad0]
// ---------------------------------------------------------------------------
__global__ void uv_k(const int* __restrict__ best_arcs,
                     const float* __restrict__ label_head, const float* __restrict__ label_dep,
                     float* __restrict__ U, float* __restrict__ V) {
    int t = blockIdx.x;
    int ba = best_arcs[t];
    for (int j = threadIdx.x; j < 516; j += blockDim.x) {
        float u = (j < 512) ? label_head[(size_t)ba * 512 + j] : (j == 512 ? 1.f : 0.f);
        float v = (j < 512) ? label_dep[(size_t)t * 512 + j] : (j == 512 ? 1.f : 0.f);
        U[t * 516 + j] = u;
        V[t * 516 + j] = v;
    }
}

// ---------------------------------------------------------------------------
// Label biaffine: sel[l,t] += ((U[t]@B_l[:,ktile]) . V[t,ktile])
// ---------------------------------------------------------------------------
__global__ __launch_bounds__(256) void label_k(
    const float* __restrict__ U, const float* __restrict__ V,
    const float* __restrict__ BW, float* __restrict__ sel) {
    __shared__ float Us[16][65];
    __shared__ float Bs[16][65];
    __shared__ float selred[64];
    int l = blockIdx.z;
    int t0 = blockIdx.y * 64, k0 = blockIdx.x * 64;
    const float* Bl = BW + (size_t)l * 513 * 513;
    int tx = threadIdx.x & 15, ty = threadIdx.x >> 4;
    float acc[4][4] = {};
    for (int h0 = 0; h0 < 513; h0 += 16) {
#pragma unroll
        for (int i = 0; i < 4; ++i) {
            int e = threadIdx.x + i * 256;
            int a = e >> 4, hh = e & 15;
            int h = h0 + hh;
            Us[hh][a] = (h < 513) ? U[(size_t)(t0 + a) * 516 + h] : 0.f;
            int kc = k0 + a;
            Bs[hh][a] = (h < 513 && kc < 513) ? Bl[(size_t)h * 513 + kc] : 0.f;
        }
        __syncthreads();
#pragma unroll
        for (int hh = 0; hh < 16; ++hh) {
            float a0 = Us[hh][ty * 4 + 0], a1 = Us[hh][ty * 4 + 1];
            float a2 = Us[hh][ty * 4 + 2], a3 = Us[hh][ty * 4 + 3];
            float b0 = Bs[hh][tx * 4 + 0], b1 = Bs[hh][tx * 4 + 1];
            float b2 = Bs[hh][tx * 4 + 2], b3 = Bs[hh][tx * 4 + 3];
            acc[0][0] += a0 * b0; acc[0][1] += a0 * b1; acc[0][2] += a0 * b2; acc[0][3] += a0 * b3;
            acc[1][0] += a1 * b0; acc[1][1] += a1 * b1; acc[1][2] += a1 * b2; acc[1][3] += a1 * b3;
            acc[2][0] += a2 * b0; acc[2][1] += a2 * b1; acc[2][2] += a2 * b2; acc[2][3] += a2 * b3;
            acc[3][0] += a3 * b0; acc[3][1] += a3 * b1; acc[3][2] += a3 * b2; acc[3][3] += a3 * b3;
        }
        __syncthreads();
    }
    if (threadIdx.x < 64) selred[threadIdx.x] = 0.f;
    __syncthreads();
#pragma unroll
    for (int i = 0; i < 4; ++i) {
        int t = t0 + ty * 4 + i;
        float sacc = 0.f;
#pragma unroll
        for (int j = 0; j < 4; ++j) {
            int k = k0 + tx * 4 + j;
            float vv = (k < 513) ? V[(size_t)t * 516 + k] : 0.f;
            sacc += acc[i][j] * vv;
        }
        atomicAdd(&selred[ty * 4 + i], sacc);
    }
    __syncthreads();
    if (threadIdx.x < 64)
        atomicAdd(&sel[(size_t)l * 512 + t0 + threadIdx.x], selred[threadIdx.x]);
}

// ---------------------------------------------------------------------------
// Row softmax in place (512x512), one WG per row
// ---------------------------------------------------------------------------
__global__ __launch_bounds__(256) void softmax_rows(float* __restrict__ Smat) {
    __shared__ float sdata[256];
    int i = blockIdx.x, tid = threadIdx.x;
    float* row = Smat + (size_t)i * 512;
    float m = -1e30f;
    for (int j = tid; j < 512; j += 256) m = fmaxf(m, row[j]);
    sdata[tid] = m; __syncthreads();
    for (int off = 128; off > 0; off >>= 1) {
        if (tid < off) sdata[tid] = fmaxf(sdata[tid], sdata[tid + off]);
        __syncthreads();
    }
    m = sdata[0]; __syncthreads();
    float ssum = 0.f;
    for (int j = tid; j < 512; j += 256) { float e = __expf(row[j] - m); row[j] = e; ssum += e; }
    sdata[tid] = ssum; __syncthreads();
    for (int off = 128; off > 0; off >>= 1) {
        if (tid < off) sdata[tid] += sdata[tid + off];
        __syncthreads();
    }
    float inv = 1.f / sdata[0];
    for (int j = tid; j < 512; j += 256) row[j] *= inv;
}

// ---------------------------------------------------------------------------
// log_softmax over l (50) for each t (512)
// ---------------------------------------------------------------------------
__global__ void lsm_k(const float* __restrict__ sel, float* __restrict__ out1) {
    int t = blockIdx.x * blockDim.x + threadIdx.x;
    if (t >= 512) return;
    float m = -1e30f;
    for (int l = 0; l < 50; ++l) m = fmaxf(m, sel[l * 512 + t]);
    float ssum = 0.f;
    for (int l = 0; l < 50; ++l) ssum += __expf(sel[l * 512 + t] - m);
    float lse = m + __logf(ssum);
    for (int l = 0; l < 50; ++l) out1[l * 512 + t] = sel[l * 512 + t] - lse;
}

// ---------------------------------------------------------------------------
extern "C" void kernel_launch(void* const* d_in, const int* in_sizes, int n_in,
                              void* d_out, int out_size, void* d_ws, size_t ws_size,
                              hipStream_t stream) {
    const int* sentence     = (const int*)d_in[0];
    const int* tags         = (const int*)d_in[1];
    const int* chars        = (const int*)d_in[2];
    const int* char_lengths = (const int*)d_in[3];
    const int* best_arcs    = (const int*)d_in[4];
    const float* word_emb   = (const float*)d_in[5];
    const float* tag_emb    = (const float*)d_in[6];
    const float* char_emb   = (const float*)d_in[7];
    const float* att_W      = (const float*)d_in[8];
    const float* att_b      = (const float*)d_in[9];
    const float* W_ih_f     = (const float*)d_in[10];
    const float* W_hh_f     = (const float*)d_in[11];
    const float* b_f        = (const float*)d_in[12];
    const float* W_ih_b     = (const float*)d_in[13];
    const float* W_hh_b     = (const float*)d_in[14];
    const float* b_b        = (const float*)d_in[15];
    const float* cW_ih      = (const float*)d_in[16];
    const float* cW_hh      = (const float*)d_in[17];
    const float* cb         = (const float*)d_in[18];
    const float* arc_dep_W  = (const float*)d_in[19];
    const float* arc_dep_b  = (const float*)d_in[20];
    const float* arc_head_W = (const float*)d_in[21];
    const float* arc_head_b = (const float*)d_in[22];
    const float* label_dep_W  = (const float*)d_in[23];
    const float* label_dep_b  = (const float*)d_in[24];
    const float* label_head_W = (const float*)d_in[25];
    const float* label_head_b = (const float*)d_in[26];
    const float* biaff_arc_W   = (const float*)d_in[27];
    const float* biaff_label_W = (const float*)d_in[28];

    float* ws = (float*)d_ws;
    float* out = (float*)d_out;

    // workspace layout (float offsets)
    const size_t o_embeds = 0;        // 512*400
    const size_t o_xf     = 204800;   // 512*2048
    const size_t o_xb     = 1253376;  // 512*2048
    const size_t o_lstm   = 2301952;  // 512*1024
    const size_t o_heads  = 2826240;  // 4 * 512*512
    const size_t o_P      = 3874816;  // 512*512
    const size_t o_U      = 4136960;  // 512*516
    const size_t o_V      = 4401152;  // 512*516
    const size_t o_sel    = 4665344;  // 50*512
    const size_t o_hG     = 4690944;  // 2 dirs * 2 parity bufs * 256 qwords = 8 KB

    // zero h exchange buffers (value=0, tag=0 == initial state) + sel accumulator
    hipMemsetAsync(ws + o_hG, 0, 8192, stream);
    hipMemsetAsync(ws + o_sel, 0, 25600 * sizeof(float), stream);

    gather_k<<<512, 128, 0, stream>>>(sentence, tags, word_emb, tag_emb, ws + o_embeds);
    char_k<<<512, 64, 0, stream>>>(chars, char_lengths, char_emb, att_W, att_b,
                                   cW_ih, cW_hh, cb, out + 287744);

    // fused input projections (z=0 fwd, z=1 bwd with reversed rows)
    gemm_xproj<<<dim3(32, 8, 2), 256, 0, stream>>>(ws + o_embeds,
                                                   W_ih_f, b_f, ws + o_xf,
                                                   W_ih_b, b_b, ws + o_xb);

    lstm_rec<<<32, 256, 0, stream>>>(W_hh_f, W_hh_b, ws + o_xf, ws + o_xb,
                                     ws + o_lstm, (unsigned long long*)(ws + o_hG));

    // 4 MLP heads fused: relu(lstm_out @ W^T + b)
    gemm_heads<<<dim3(8, 8, 4), 256, 0, stream>>>(ws + o_lstm,
        arc_dep_W,    arc_dep_b,    ws + o_heads + 0,
        arc_head_W,   arc_head_b,   ws + o_heads + 262144,
        label_dep_W,  label_dep_b,  ws + o_heads + 524288,
        label_head_W, label_head_b, ws + o_heads + 786432);

    uv_k<<<512, 128, 0, stream>>>(best_arcs, ws + o_heads + 786432, ws + o_heads + 524288,
                                  ws + o_U, ws + o_V);

    // P = arc_head_a @ biaff_arc_W^T (ones column folded as bias)
    gemm_abT<<<dim3(8, 8), 256, 0, stream>>>(ws + o_heads + 262144, 512, biaff_arc_W, 513,
                                             biaff_arc_W + 512, 513,
                                             ws + o_P, 512, 512, 512, 512, 0, 0);
    // S = P @ arc_dep^T -> out0, then row-softmax in place
    gemm_abT<<<dim3(8, 8), 256, 0, stream>>>(ws + o_P, 512, ws + o_heads + 0, 512, nullptr, 0,
                                             out, 512, 512, 512, 512, 0, 0);
    softmax_rows<<<512, 256, 0, stream>>>(out);

    label_k<<<dim3(9, 8, 50), 256, 0, stream>>>(ws + o_U, ws + o_V, biaff_label_W, ws + o_sel);
    lsm_k<<<2, 256, 0, stream>>>(ws + o_sel, out + 262144);
}

// Round 4
// 1526.523 us; speedup vs baseline: 3.1411x; 1.2183x over previous
//
#include <hip/hip_runtime.h>
#include <hip/hip_fp16.h>

// ---------------------------------------------------------------------------
// Problem constants
//   S=512 tokens, WD=300, TD=100, CE=20, CH=20, H=512, LAB=50, MAXW=16
// Outputs: arc_scores (512x512) | label_scores (50x512) | char_embeds (20x512)
// ---------------------------------------------------------------------------

static __device__ __forceinline__ float sigm(float x) { return 1.f / (1.f + __expf(-x)); }
static __device__ __forceinline__ float ftanh(float x) {
    x = fminf(15.f, fmaxf(-15.f, x));
    float e = __expf(2.f * x);
    return (e - 1.f) / (e + 1.f);
}

typedef _Float16 h2_t __attribute__((ext_vector_type(2)));
typedef _Float16 h8_t __attribute__((ext_vector_type(8)));
typedef float f4_t __attribute__((ext_vector_type(4)));
union U32H2 { unsigned u; h2_t h; unsigned short s[2]; };

static __device__ __forceinline__ float dot2f(unsigned wa, unsigned hb, float c) {
#if __has_builtin(__builtin_amdgcn_fdot2)
    U32H2 a, b; a.u = wa; b.u = hb;
    return __builtin_amdgcn_fdot2(a.h, b.h, c, false);
#else
    U32H2 a, b; a.u = wa; b.u = hb;
    return c + (float)a.h[0] * (float)b.h[0] + (float)a.h[1] * (float)b.h[1];
#endif
}
static __device__ __forceinline__ unsigned short f2h16(float x) {
    return __half_as_ushort(__float2half(x));
}

// ---------------------------------------------------------------------------
// Embedding gather
// ---------------------------------------------------------------------------
__global__ void gather_k(const int* __restrict__ sentence, const int* __restrict__ tags,
                         const float* __restrict__ word_emb, const float* __restrict__ tag_emb,
                         float* __restrict__ embeds) {
    int t = blockIdx.x;
    int w = sentence[t], tg = tags[t];
    for (int j = threadIdx.x; j < 400; j += blockDim.x) {
        float v = (j < 300) ? word_emb[w * 300 + j] : tag_emb[tg * 100 + (j - 300)];
        embeds[t * 400 + j] = v;
    }
}

// ---------------------------------------------------------------------------
// Shared fp32 GEMM tile body: C[64x64 tile] = A[M,K] @ B[N,K]^T (+bias)(relu)
// ---------------------------------------------------------------------------
static __device__ __forceinline__ void gemm_body(
    const float* __restrict__ A, int lda, const float* __restrict__ B, int ldb,
    const float* __restrict__ bias, int bias_stride,
    float* __restrict__ C, int ldc, int M, int K, int revA, int doRelu) {
    __shared__ float As[16][65];
    __shared__ float Bs[16][65];
    int tx = threadIdx.x & 15, ty = threadIdx.x >> 4;
    int bm = blockIdx.y * 64, bn = blockIdx.x * 64;
    float acc[4][4] = {};
    for (int k0 = 0; k0 < K; k0 += 16) {
#pragma unroll
        for (int i = 0; i < 4; ++i) {
            int e = threadIdx.x + i * 256;
            int m = e >> 4, kk = e & 15;
            int row = bm + m; if (revA) row = M - 1 - row;
            As[kk][m] = A[(size_t)row * lda + k0 + kk];
            Bs[kk][m] = B[(size_t)(bn + m) * ldb + k0 + kk];
        }
        __syncthreads();
#pragma unroll
        for (int kk = 0; kk < 16; ++kk) {
            float a0 = As[kk][ty * 4 + 0], a1 = As[kk][ty * 4 + 1];
            float a2 = As[kk][ty * 4 + 2], a3 = As[kk][ty * 4 + 3];
            float b0 = Bs[kk][tx * 4 + 0], b1 = Bs[kk][tx * 4 + 1];
            float b2 = Bs[kk][tx * 4 + 2], b3 = Bs[kk][tx * 4 + 3];
            acc[0][0] += a0 * b0; acc[0][1] += a0 * b1; acc[0][2] += a0 * b2; acc[0][3] += a0 * b3;
            acc[1][0] += a1 * b0; acc[1][1] += a1 * b1; acc[1][2] += a1 * b2; acc[1][3] += a1 * b3;
            acc[2][0] += a2 * b0; acc[2][1] += a2 * b1; acc[2][2] += a2 * b2; acc[2][3] += a2 * b3;
            acc[3][0] += a3 * b0; acc[3][1] += a3 * b1; acc[3][2] += a3 * b2; acc[3][3] += a3 * b3;
        }
        __syncthreads();
    }
#pragma unroll
    for (int i = 0; i < 4; ++i) {
#pragma unroll
        for (int j = 0; j < 4; ++j) {
            int n = bn + tx * 4 + j;
            float v = acc[i][j];
            if (bias) v += bias[(size_t)n * bias_stride];
            if (doRelu) v = fmaxf(v, 0.f);
            C[(size_t)(bm + ty * 4 + i) * ldc + n] = v;
        }
    }
}

__global__ __launch_bounds__(256) void gemm_abT(
    const float* __restrict__ A, int lda, const float* __restrict__ B, int ldb,
    const float* __restrict__ bias, int bias_stride,
    float* __restrict__ C, int ldc, int M, int N, int K, int revA, int doRelu) {
    gemm_body(A, lda, B, ldb, bias, bias_stride, C, ldc, M, K, revA, doRelu);
}

// 4 MLP heads fused on grid.z: relu(lstm_out @ W^T + b), M=N=512, K=1024
__global__ __launch_bounds__(256) void gemm_heads(
    const float* __restrict__ A,
    const float* W0, const float* B0, float* C0,
    const float* W1, const float* B1, float* C1,
    const float* W2, const float* B2, float* C2,
    const float* W3, const float* B3, float* C3) {
    const float* W; const float* bias; float* C;
    switch (blockIdx.z) {
        case 0: W = W0; bias = B0; C = C0; break;
        case 1: W = W1; bias = B1; C = C1; break;
        case 2: W = W2; bias = B2; C = C2; break;
        default: W = W3; bias = B3; C = C3; break;
    }
    gemm_body(A, 1024, W, 1024, bias, 1, C, 512, 512, 1024, 0, 1);
}

// 2 input projections fused on grid.z (z=1 reverses A rows), M=512,N=2048,K=400
__global__ __launch_bounds__(256) void gemm_xproj(
    const float* __restrict__ A,
    const float* Wf, const float* bf, float* Cf,
    const float* Wb, const float* bb, float* Cb) {
    const float* W = blockIdx.z ? Wb : Wf;
    const float* bias = blockIdx.z ? bb : bf;
    float* C = blockIdx.z ? Cb : Cf;
    gemm_body(A, 400, W, 400, bias, 1, C, 2048, 512, 400, blockIdx.z, 0);
}

// ---------------------------------------------------------------------------
// Recurrent bidirectional LSTM (r3 structure, unchanged).
// ---------------------------------------------------------------------------
__global__ __launch_bounds__(256) void lstm_rec(
    const float* __restrict__ W_hh_f, const float* __restrict__ W_hh_b,
    const float* __restrict__ xpf, const float* __restrict__ xpb,
    float* __restrict__ lstm_out, unsigned long long* hq) {
    int wg = blockIdx.x;
    int dir = wg >> 4, s = wg & 15;
    int tid = threadIdx.x;
    int wv = tid >> 6;
    int lane = tid & 63;
    int g = tid & 31, p = tid >> 5;
    const float* Whh = dir ? W_hh_b : W_hh_f;
    const float* xp = dir ? xpb : xpf;

    __shared__ float red[2][1024];

    unsigned Wreg[4][32];
#pragma unroll
    for (int q = 0; q < 4; ++q) {
        int gr = q * 512 + s * 32 + g;
        const float* wrow = Whh + (size_t)gr * 512 + p * 64;
#pragma unroll
        for (int u = 0; u < 32; ++u) {
            unsigned lo = f2h16(wrow[2 * u]);
            unsigned hi = f2h16(wrow[2 * u + 1]);
            Wreg[q][u] = lo | (hi << 16);
        }
    }

    float c = 0.f;
    unsigned long long* hbase = hq + dir * 512;
    int qidx = wv * 64 + lane;

    for (int t = 0; t < 512; ++t) {
        float x0 = 0.f, x1 = 0.f, x2 = 0.f, x3 = 0.f;
        if (tid < 32) {
            const float* x = xp + (size_t)t * 2048;
            int col = s * 32 + tid;
            x0 = x[col]; x1 = x[512 + col]; x2 = x[1024 + col]; x3 = x[1536 + col];
        }

        unsigned long long* hin = hbase + (t & 1) * 256;
        unsigned tag = (unsigned)t & 0xffffu;
        unsigned long long v = __hip_atomic_load(hin + qidx, __ATOMIC_RELAXED,
                                                 __HIP_MEMORY_SCOPE_AGENT);
        while ((((unsigned)(v >> 16)) & 0xffffu) != tag || ((unsigned)(v >> 48)) != tag)
            v = __hip_atomic_load(hin + qidx, __ATOMIC_RELAXED, __HIP_MEMORY_SCOPE_AGENT);
        unsigned hw = (unsigned)(v & 0xffffu) | (((unsigned)((v >> 32) & 0xffffu)) << 16);

        float a0 = 0.f, a1 = 0.f, a2 = 0.f, a3 = 0.f;
        int half_base = lane & 32;
#pragma unroll
        for (int u = 0; u < 32; ++u) {
            unsigned hwu = (unsigned)__shfl((int)hw, half_base + u);
            a0 = dot2f(Wreg[0][u], hwu, a0);
            a1 = dot2f(Wreg[1][u], hwu, a1);
            a2 = dot2f(Wreg[2][u], hwu, a2);
            a3 = dot2f(Wreg[3][u], hwu, a3);
        }
        float* r = &red[t & 1][p * 128 + g * 4];
        r[0] = a0; r[1] = a1; r[2] = a2; r[3] = a3;
        __syncthreads();

        if (tid < 32) {
            float z0 = 0.f, z1 = 0.f, z2 = 0.f, z3 = 0.f;
            const float* rb = red[t & 1];
#pragma unroll
            for (int pp = 0; pp < 8; ++pp) {
                const float* rr = rb + pp * 128 + tid * 4;
                z0 += rr[0]; z1 += rr[1]; z2 += rr[2]; z3 += rr[3];
            }
            z0 += x0; z1 += x1; z2 += x2; z3 += x3;
            c = sigm(z1) * c + sigm(z0) * ftanh(z2);
            float hn = sigm(z3) * ftanh(c);
            int col = s * 32 + tid;
            int row = dir ? (511 - t) : t;
            lstm_out[(size_t)row * 1024 + dir * 512 + col] = hn;

            unsigned tw = (unsigned)f2h16(hn) | (((unsigned)(t + 1) & 0xffffu) << 16);
            unsigned other = (unsigned)__shfl_down((int)tw, 1);
            if ((tid & 1) == 0) {
                unsigned long long qv = (unsigned long long)tw |
                                        ((unsigned long long)other << 32);
                __hip_atomic_store(hbase + ((t + 1) & 1) * 256 + (col >> 1), qv,
                                   __ATOMIC_RELAXED, __HIP_MEMORY_SCOPE_AGENT);
            }
        }
    }
}

// ---------------------------------------------------------------------------
// Per-word char LSTM + masked gram attention (one 64-thread WG per word)
// ---------------------------------------------------------------------------
__global__ __launch_bounds__(64) void char_k(
    const int* __restrict__ chars, const int* __restrict__ char_lengths,
    const float* __restrict__ char_emb, const float* __restrict__ att_W,
    const float* __restrict__ att_b, const float* __restrict__ cW_ih,
    const float* __restrict__ cW_hh, const float* __restrict__ cb,
    float* __restrict__ out2) {
    int w = blockIdx.x, tid = threadIdx.x;
    __shared__ float Wih[1600], Whh[1600], cbs[80], attsh[20];
    __shared__ float xsh[20], hsh[20], prodsh[20];
    for (int i = tid; i < 1600; i += 64) { Wih[i] = cW_ih[i]; Whh[i] = cW_hh[i]; }
    for (int i = tid; i < 80; i += 64) cbs[i] = cb[i];
    if (tid < 20) { attsh[tid] = att_W[tid]; hsh[tid] = 0.f; }
    __syncthreads();

    int L = char_lengths[w];
    float c = 0.f, accj = 0.f;
    for (int t = 0; t < 16; ++t) {
        if (tid < 20) xsh[tid] = char_emb[(size_t)chars[w * 16 + t] * 20 + tid];
        __syncthreads();
        float hn = 0.f;
        if (tid < 20) {
            float z[4];
#pragma unroll
            for (int q = 0; q < 4; ++q) {
                int r = q * 20 + tid;
                float sacc = cbs[r];
                for (int d = 0; d < 20; ++d)
                    sacc += Wih[r * 20 + d] * xsh[d] + Whh[r * 20 + d] * hsh[d];
                z[q] = sacc;
            }
            c = sigm(z[1]) * c + sigm(z[0]) * ftanh(z[2]);
            hn = sigm(z[3]) * ftanh(c);
        }
        __syncthreads();
        if (tid < 20) { hsh[tid] = hn; prodsh[tid] = hn * attsh[tid]; }
        __syncthreads();
        if (tid < 20 && t < L) {
            float st = 0.f;
            for (int k = 0; k < 20; ++k) st += prodsh[k];
            accj += hn * st;
        }
        __syncthreads();
    }
    if (tid < 20) out2[tid * 512 + w] = accj + att_b[0];
}

// ---------------------------------------------------------------------------
// Build U[t] = [label_head[best_arcs[t]], 1, pad0], V[t] = [label_dep[t], 1, pad0]
// ---------------------------------------------------------------------------
__global__ void uv_k(const int* __restrict__ best_arcs,
                     const float* __restrict__ label_head, const float* __restrict__ label_dep,
                     float* __restrict__ U, float* __restrict__ V) {
    int t = blockIdx.x;
    int ba = best_arcs[t];
    for (int j = threadIdx.x; j < 516; j += blockDim.x) {
        float u = (j < 512) ? label_head[(size_t)ba * 512 + j] : (j == 512 ? 1.f : 0.f);
        float v = (j < 512) ? label_dep[(size_t)t * 512 + j] : (j == 512 ? 1.f : 0.f);
        U[t * 516 + j] = u;
        V[t * 516 + j] = v;
    }
}

// ---------------------------------------------------------------------------
// U fp32 [512][516] -> Uh fp16 [512][544] (zero-padded h>=513)
// ---------------------------------------------------------------------------
__global__ void uconv_k(const float* __restrict__ U, _Float16* __restrict__ Uh) {
    int t = blockIdx.x;
    for (int h = threadIdx.x; h < 544; h += blockDim.x)
        Uh[(size_t)t * 544 + h] = (_Float16)((h < 513) ? U[(size_t)t * 516 + h] : 0.f);
}

// ---------------------------------------------------------------------------
// biaff_label_W fp32 [l][513 h][513 k] -> Bh fp16 [l][576 k][544 h]
// (transposed + zero-padded) via LDS tile transpose.
// grid (9 h-tiles, 9 k-tiles, 50 l), block 256.
// ---------------------------------------------------------------------------
__global__ __launch_bounds__(256) void bconv_k(const float* __restrict__ B,
                                               _Float16* __restrict__ Bh) {
    __shared__ _Float16 Ts[64][68];
    int h0 = blockIdx.x * 64, k0 = blockIdx.y * 64, l = blockIdx.z;
    int tid = threadIdx.x;
    const float* Bl = B + (size_t)l * 513 * 513;
    _Float16* BhL = Bh + (size_t)l * 576 * 544;

    int tr = tid >> 4, tc = tid & 15;
#pragma unroll
    for (int i = 0; i < 4; ++i) {
        int hl = tr + i * 16;
        int h = h0 + hl;
#pragma unroll
        for (int j = 0; j < 4; ++j) {
            int k = k0 + tc * 4 + j;
            float v = (h < 513 && k < 513) ? Bl[(size_t)h * 513 + k] : 0.f;
            Ts[hl][tc * 4 + j] = (_Float16)v;
        }
    }
    __syncthreads();

    int cr = tid >> 2;            // k-local 0..63
    int hb = (tid & 3) * 16;      // h-local block
    int hg = h0 + hb;
    if (hg < 544) {
        __align__(16) _Float16 tmp[16];
#pragma unroll
        for (int j = 0; j < 16; ++j) tmp[j] = Ts[hb + j][cr];
        uint4* dst = (uint4*)(BhL + (size_t)(k0 + cr) * 544 + hg);
        dst[0] = ((const uint4*)tmp)[0];
        dst[1] = ((const uint4*)tmp)[1];
    }
}

// ---------------------------------------------------------------------------
// MFMA label biaffine: sel[l,t] += (U[t] @ B_l[:,ktile]) . V[t,ktile]
// grid (9 k-tiles, 8 t-tiles, 50 l), block 256 (4 waves).
// Per WG: 64(t) x 64(k) tile of T = U@B_l via mfma_f32_16x16x32_f16 over
// padded K=544; epilogue fuses the V-dot, intra-quad shuffle reduce, and one
// atomicAdd per t-row. T never materialized.
// ---------------------------------------------------------------------------
__global__ __launch_bounds__(256) void label_mfma(
    const _Float16* __restrict__ Uh,   // [512][544]
    const _Float16* __restrict__ Bh,   // [50][576][544]
    const float* __restrict__ V,       // [512][516]
    float* __restrict__ sel) {         // [50][512]
    __shared__ _Float16 Us[64][40];    // row stride 40 f16: 2-way banks (free)
    __shared__ _Float16 Bs[64][40];
    int l = blockIdx.z;
    int t0 = blockIdx.y * 64, k0 = blockIdx.x * 64;
    int tid = threadIdx.x;
    int w = tid >> 6, lane = tid & 63, m = lane & 15, q = lane >> 4;
    const _Float16* Bl = Bh + (size_t)l * 576 * 544;
    int srow = tid >> 2, scol = (tid & 3) * 8;

    f4_t acc[4];
#pragma unroll
    for (int c = 0; c < 4; ++c) acc[c] = 0;

    for (int h0 = 0; h0 < 544; h0 += 32) {
        uint4 ud = *(const uint4*)(Uh + (size_t)(t0 + srow) * 544 + h0 + scol);
        uint4 bd = *(const uint4*)(Bl + (size_t)(k0 + srow) * 544 + h0 + scol);
        __syncthreads();   // protect LDS from previous iteration's frag reads
        *(uint4*)(&Us[srow][scol]) = ud;
        *(uint4*)(&Bs[srow][scol]) = bd;
        __syncthreads();

        h8_t a  = *(const h8_t*)(&Us[w * 16 + m][q * 8]);
        h8_t b0 = *(const h8_t*)(&Bs[ 0 + m][q * 8]);
        h8_t b1 = *(const h8_t*)(&Bs[16 + m][q * 8]);
        h8_t b2 = *(const h8_t*)(&Bs[32 + m][q * 8]);
        h8_t b3 = *(const h8_t*)(&Bs[48 + m][q * 8]);
        acc[0] = __builtin_amdgcn_mfma_f32_16x16x32_f16(a, b0, acc[0], 0, 0, 0);
        acc[1] = __builtin_amdgcn_mfma_f32_16x16x32_f16(a, b1, acc[1], 0, 0, 0);
        acc[2] = __builtin_amdgcn_mfma_f32_16x16x32_f16(a, b2, acc[2], 0, 0, 0);
        acc[3] = __builtin_amdgcn_mfma_f32_16x16x32_f16(a, b3, acc[3], 0, 0, 0);
    }

    // epilogue: D[row=q*4+r][col=c*16+m] * V[t][k], reduce over 64 k-cols
    float* selp = sel + (size_t)l * 512;
#pragma unroll
    for (int r = 0; r < 4; ++r) {
        int t = t0 + w * 16 + q * 4 + r;
        float vsum = 0.f;
#pragma unroll
        for (int c = 0; c < 4; ++c) {
            int k = k0 + c * 16 + m;
            float vv = (k < 513) ? V[(size_t)t * 516 + k] : 0.f;
            vsum += acc[c][r] * vv;
        }
#pragma unroll
        for (int off = 1; off < 16; off <<= 1)
            vsum += __shfl_xor(vsum, off);
        if (m == 0) atomicAdd(selp + t, vsum);
    }
}

// ---------------------------------------------------------------------------
// fp32 fallback label biaffine (used when ws_size can't hold Bh)
// ---------------------------------------------------------------------------
__global__ __launch_bounds__(256) void label_k(
    const float* __restrict__ U, const float* __restrict__ V,
    const float* __restrict__ BW, float* __restrict__ sel) {
    __shared__ float Us[16][65];
    __shared__ float Bs[16][65];
    __shared__ float selred[64];
    int l = blockIdx.z;
    int t0 = blockIdx.y * 64, k0 = blockIdx.x * 64;
    const float* Bl = BW + (size_t)l * 513 * 513;
    int tx = threadIdx.x & 15, ty = threadIdx.x >> 4;
    float acc[4][4] = {};
    for (int h0 = 0; h0 < 513; h0 += 16) {
#pragma unroll
        for (int i = 0; i < 4; ++i) {
            int e = threadIdx.x + i * 256;
            int a = e >> 4, hh = e & 15;
            int h = h0 + hh;
            Us[hh][a] = (h < 513) ? U[(size_t)(t0 + a) * 516 + h] : 0.f;
            int kc = k0 + a;
            Bs[hh][a] = (h < 513 && kc < 513) ? Bl[(size_t)h * 513 + kc] : 0.f;
        }
        __syncthreads();
#pragma unroll
        for (int hh = 0; hh < 16; ++hh) {
            float a0 = Us[hh][ty * 4 + 0], a1 = Us[hh][ty * 4 + 1];
            float a2 = Us[hh][ty * 4 + 2], a3 = Us[hh][ty * 4 + 3];
            float b0 = Bs[hh][tx * 4 + 0], b1 = Bs[hh][tx * 4 + 1];
            float b2 = Bs[hh][tx * 4 + 2], b3 = Bs[hh][tx * 4 + 3];
            acc[0][0] += a0 * b0; acc[0][1] += a0 * b1; acc[0][2] += a0 * b2; acc[0][3] += a0 * b3;
            acc[1][0] += a1 * b0; acc[1][1] += a1 * b1; acc[1][2] += a1 * b2; acc[1][3] += a1 * b3;
            acc[2][0] += a2 * b0; acc[2][1] += a2 * b1; acc[2][2] += a2 * b2; acc[2][3] += a2 * b3;
            acc[3][0] += a3 * b0; acc[3][1] += a3 * b1; acc[3][2] += a3 * b2; acc[3][3] += a3 * b3;
        }
        __syncthreads();
    }
    if (threadIdx.x < 64) selred[threadIdx.x] = 0.f;
    __syncthreads();
#pragma unroll
    for (int i = 0; i < 4; ++i) {
        int t = t0 + ty * 4 + i;
        float sacc = 0.f;
#pragma unroll
        for (int j = 0; j < 4; ++j) {
            int k = k0 + tx * 4 + j;
            float vv = (k < 513) ? V[(size_t)t * 516 + k] : 0.f;
            sacc += acc[i][j] * vv;
        }
        atomicAdd(&selred[ty * 4 + i], sacc);
    }
    __syncthreads();
    if (threadIdx.x < 64)
        atomicAdd(&sel[(size_t)l * 512 + t0 + threadIdx.x], selred[threadIdx.x]);
}

// ---------------------------------------------------------------------------
// Row softmax in place (512x512), one WG per row
// ---------------------------------------------------------------------------
__global__ __launch_bounds__(256) void softmax_rows(float* __restrict__ Smat) {
    __shared__ float sdata[256];
    int i = blockIdx.x, tid = threadIdx.x;
    float* row = Smat + (size_t)i * 512;
    float m = -1e30f;
    for (int j = tid; j < 512; j += 256) m = fmaxf(m, row[j]);
    sdata[tid] = m; __syncthreads();
    for (int off = 128; off > 0; off >>= 1) {
        if (tid < off) sdata[tid] = fmaxf(sdata[tid], sdata[tid + off]);
        __syncthreads();
    }
    m = sdata[0]; __syncthreads();
    float ssum = 0.f;
    for (int j = tid; j < 512; j += 256) { float e = __expf(row[j] - m); row[j] = e; ssum += e; }
    sdata[tid] = ssum; __syncthreads();
    for (int off = 128; off > 0; off >>= 1) {
        if (tid < off) sdata[tid] += sdata[tid + off];
        __syncthreads();
    }
    float inv = 1.f / sdata[0];
    for (int j = tid; j < 512; j += 256) row[j] *= inv;
}

// ---------------------------------------------------------------------------
// log_softmax over l (50) for each t (512)
// ---------------------------------------------------------------------------
__global__ void lsm_k(const float* __restrict__ sel, float* __restrict__ out1) {
    int t = blockIdx.x * blockDim.x + threadIdx.x;
    if (t >= 512) return;
    float m = -1e30f;
    for (int l = 0; l < 50; ++l) m = fmaxf(m, sel[l * 512 + t]);
    float ssum = 0.f;
    for (int l = 0; l < 50; ++l) ssum += __expf(sel[l * 512 + t] - m);
    float lse = m + __logf(ssum);
    for (int l = 0; l < 50; ++l) out1[l * 512 + t] = sel[l * 512 + t] - lse;
}

// ---------------------------------------------------------------------------
extern "C" void kernel_launch(void* const* d_in, const int* in_sizes, int n_in,
                              void* d_out, int out_size, void* d_ws, size_t ws_size,
                              hipStream_t stream) {
    const int* sentence     = (const int*)d_in[0];
    const int* tags         = (const int*)d_in[1];
    const int* chars        = (const int*)d_in[2];
    const int* char_lengths = (const int*)d_in[3];
    const int* best_arcs    = (const int*)d_in[4];
    const float* word_emb   = (const float*)d_in[5];
    const float* tag_emb    = (const float*)d_in[6];
    const float* char_emb   = (const float*)d_in[7];
    const float* att_W      = (const float*)d_in[8];
    const float* att_b      = (const float*)d_in[9];
    const float* W_ih_f     = (const float*)d_in[10];
    const float* W_hh_f     = (const float*)d_in[11];
    const float* b_f        = (const float*)d_in[12];
    const float* W_ih_b     = (const float*)d_in[13];
    const float* W_hh_b     = (const float*)d_in[14];
    const float* b_b        = (const float*)d_in[15];
    const float* cW_ih      = (const float*)d_in[16];
    const float* cW_hh      = (const float*)d_in[17];
    const float* cb         = (const float*)d_in[18];
    const float* arc_dep_W  = (const float*)d_in[19];
    const float* arc_dep_b  = (const float*)d_in[20];
    const float* arc_head_W = (const float*)d_in[21];
    const float* arc_head_b = (const float*)d_in[22];
    const float* label_dep_W  = (const float*)d_in[23];
    const float* label_dep_b  = (const float*)d_in[24];
    const float* label_head_W = (const float*)d_in[25];
    const float* label_head_b = (const float*)d_in[26];
    const float* biaff_arc_W   = (const float*)d_in[27];
    const float* biaff_label_W = (const float*)d_in[28];

    float* ws = (float*)d_ws;
    float* out = (float*)d_out;

    // workspace layout (float offsets)
    const size_t o_embeds = 0;        // 512*400
    const size_t o_xf     = 204800;   // 512*2048
    const size_t o_xb     = 1253376;  // 512*2048
    const size_t o_lstm   = 2301952;  // 512*1024
    const size_t o_heads  = 2826240;  // 4 * 512*512
    const size_t o_P      = 3874816;  // 512*512
    const size_t o_U      = 4136960;  // 512*516
    const size_t o_V      = 4401152;  // 512*516
    const size_t o_sel    = 4665344;  // 50*512
    const size_t o_hG     = 4690944;  // 1024 qwords = 2048 floats
    const size_t o_Uh     = 4692992;  // fp16 512*544 = 139264 floats
    const size_t o_Bh     = 4832256;  // fp16 50*576*544 = 7833600 floats
    const size_t ws_need  = (o_Bh + 7833600) * 4;  // 50,663,424 B

    const bool use_mfma_label = (ws_size >= ws_need);

    hipMemsetAsync(ws + o_hG, 0, 8192, stream);
    hipMemsetAsync(ws + o_sel, 0, 25600 * sizeof(float), stream);

    gather_k<<<512, 128, 0, stream>>>(sentence, tags, word_emb, tag_emb, ws + o_embeds);
    char_k<<<512, 64, 0, stream>>>(chars, char_lengths, char_emb, att_W, att_b,
                                   cW_ih, cW_hh, cb, out + 287744);

    // B transpose+fp16 conversion early: independent of everything else
    if (use_mfma_label)
        bconv_k<<<dim3(9, 9, 50), 256, 0, stream>>>(biaff_label_W, (_Float16*)(ws + o_Bh));

    // fused input projections (z=0 fwd, z=1 bwd with reversed rows)
    gemm_xproj<<<dim3(32, 8, 2), 256, 0, stream>>>(ws + o_embeds,
                                                   W_ih_f, b_f, ws + o_xf,
                                                   W_ih_b, b_b, ws + o_xb);

    lstm_rec<<<32, 256, 0, stream>>>(W_hh_f, W_hh_b, ws + o_xf, ws + o_xb,
                                     ws + o_lstm, (unsigned long long*)(ws + o_hG));

    // 4 MLP heads fused: relu(lstm_out @ W^T + b)
    gemm_heads<<<dim3(8, 8, 4), 256, 0, stream>>>(ws + o_lstm,
        arc_dep_W,    arc_dep_b,    ws + o_heads + 0,
        arc_head_W,   arc_head_b,   ws + o_heads + 262144,
        label_dep_W,  label_dep_b,  ws + o_heads + 524288,
        label_head_W, label_head_b, ws + o_heads + 786432);

    uv_k<<<512, 128, 0, stream>>>(best_arcs, ws + o_heads + 786432, ws + o_heads + 524288,
                                  ws + o_U, ws + o_V);

    // P = arc_head_a @ biaff_arc_W^T (ones column folded as bias)
    gemm_abT<<<dim3(8, 8), 256, 0, stream>>>(ws + o_heads + 262144, 512, biaff_arc_W, 513,
                                             biaff_arc_W + 512, 513,
                                             ws + o_P, 512, 512, 512, 512, 0, 0);
    // S = P @ arc_dep^T -> out0, then row-softmax in place
    gemm_abT<<<dim3(8, 8), 256, 0, stream>>>(ws + o_P, 512, ws + o_heads + 0, 512, nullptr, 0,
                                             out, 512, 512, 512, 512, 0, 0);
    softmax_rows<<<512, 256, 0, stream>>>(out);

    if (use_mfma_label) {
        uconv_k<<<512, 64, 0, stream>>>(ws + o_U, (_Float16*)(ws + o_Uh));
        label_mfma<<<dim3(9, 8, 50), 256, 0, stream>>>(
            (const _Float16*)(ws + o_Uh), (const _Float16*)(ws + o_Bh),
            ws + o_V, ws + o_sel);
    } else {
        label_k<<<dim3(9, 8, 50), 256, 0, stream>>>(ws + o_U, ws + o_V, biaff_label_W,
                                                    ws + o_sel);
    }
    lsm_k<<<2, 256, 0, stream>>>(ws + o_sel, out + 262144);
}